// Round 1
// baseline (620.619 us; speedup 1.0000x reference)
//
#include <hip/hip_runtime.h>
#include <hip/hip_bf16.h>

// MoE: T=4096 tokens, H=2048, FFN=1024, E=8, top-2.
// Sparse formulation: router -> per-expert token lists -> grouped GEMMs.

#define T_TOK 4096
#define H_DIM 2048
#define FFN_D 1024
#define NE    8

typedef __attribute__((ext_vector_type(8))) short          bf16x8;
typedef __attribute__((ext_vector_type(4))) float          f32x4;
typedef __attribute__((ext_vector_type(4))) unsigned short us4;

__device__ __forceinline__ unsigned short f2bf(float f) {
  unsigned u = __builtin_bit_cast(unsigned, f);
  u += 0x7fffu + ((u >> 16) & 1u);
  return (unsigned short)(u >> 16);
}

// ---------------- Kernel 1: router (one wave per token) ----------------
__global__ void router_kernel(const float* __restrict__ x,
                              const float* __restrict__ Wg,
                              const float* __restrict__ bias,
                              int* __restrict__ cnt,
                              int* __restrict__ rows,
                              float* __restrict__ wts) {
  const int wid  = threadIdx.x >> 6;
  const int lane = threadIdx.x & 63;
  const int t    = blockIdx.x * 4 + wid;

  float acc[NE];
#pragma unroll
  for (int e = 0; e < NE; e++) acc[e] = 0.f;

  const float* xr = x + (size_t)t * H_DIM;
  for (int h = lane; h < H_DIM; h += 64) {
    float xv = xr[h];
#pragma unroll
    for (int e = 0; e < NE; e++) acc[e] += xv * Wg[e * H_DIM + h];
  }
#pragma unroll
  for (int e = 0; e < NE; e++) {
#pragma unroll
    for (int m = 32; m >= 1; m >>= 1) acc[e] += __shfl_xor(acc[e], m, 64);
  }

  if (lane == 0) {
    float sig[NE], sc[NE];
#pragma unroll
    for (int e = 0; e < NE; e++) {
      sig[e] = 1.f / (1.f + expf(-acc[e]));
      sc[e]  = sig[e] + bias[e];
    }
    // top-1 (strict > keeps lowest index on ties, matching lax.top_k)
    int i1 = 0; float v1 = sc[0];
#pragma unroll
    for (int e = 1; e < NE; e++) if (sc[e] > v1) { v1 = sc[e]; i1 = e; }
    int i2 = -1; float v2 = -1e30f;
#pragma unroll
    for (int e = 0; e < NE; e++) if (e != i1 && sc[e] > v2) { v2 = sc[e]; i2 = e; }

    float w1 = sig[i1], w2 = sig[i2];
    float s  = w1 + w2;
    w1 /= s; w2 /= s;

    int p1 = atomicAdd(&cnt[i1], 1);
    rows[i1 * T_TOK + p1] = t;
    wts [i1 * T_TOK + p1] = w1;
    int p2 = atomicAdd(&cnt[i2], 1);
    rows[i2 * T_TOK + p2] = t;
    wts [i2 * T_TOK + p2] = w2;
  }
}

// ---------------- Kernel 2: prefix over 8 counts ----------------
__global__ void prefix_kernel(const int* __restrict__ cnt, int* __restrict__ base) {
  if (threadIdx.x == 0) {
    int s = 0;
    for (int e = 0; e < NE; e++) { base[e] = s; s += cnt[e]; }
    base[NE] = s;
  }
}

// ---------------- Kernel 3: grouped up-proj (h1=x@W1^T, h3=x@W3^T, g=silu(h1)*h3*w) ----
// Tile: BM=128 (slots), BN=64 (ffn), BK=32. 4 waves in 2x2; wave tile 64x32.
__launch_bounds__(256)
__global__ void upproj_kernel(const float* __restrict__ x,
                              const float* __restrict__ W1,
                              const float* __restrict__ W3,
                              const int* __restrict__ cnt,
                              const int* __restrict__ base,
                              const int* __restrict__ rows,
                              const float* __restrict__ wts,
                              unsigned short* __restrict__ G) {
  const int e  = blockIdx.z;
  const int m0 = blockIdx.y * 128;
  const int n0 = blockIdx.x * 64;
  const int ce = cnt[e];
  if (m0 >= ce) return;

  __shared__ __align__(16) unsigned short As [128 * 32];
  __shared__ __align__(16) unsigned short B1s[64 * 32];
  __shared__ __align__(16) unsigned short B3s[64 * 32];
  __shared__ int   t_ids[128];
  __shared__ float w_lds[128];

  const int tid = threadIdx.x;
  if (tid < 128) {
    int i = m0 + tid;
    if (i < ce) { t_ids[tid] = rows[e * T_TOK + i]; w_lds[tid] = wts[e * T_TOK + i]; }
    else        { t_ids[tid] = 0;                   w_lds[tid] = 0.f; }
  }
  __syncthreads();

  const float* W1e = W1 + (size_t)e * FFN_D * H_DIM + (size_t)n0 * H_DIM;
  const float* W3e = W3 + (size_t)e * FFN_D * H_DIM + (size_t)n0 * H_DIM;

  const int lane = tid & 63;
  const int wid  = tid >> 6;
  const int wm   = (wid & 1) * 64;
  const int wn   = (wid >> 1) * 32;
  const int qk   = (lane >> 4) * 8;  // k offset of this lane's frag
  const int lr   = lane & 15;

  f32x4 acc1[4][2], acc3[4][2];
#pragma unroll
  for (int mi = 0; mi < 4; mi++)
#pragma unroll
    for (int ni = 0; ni < 2; ni++) { acc1[mi][ni] = (f32x4)0.f; acc3[mi][ni] = (f32x4)0.f; }

  for (int kt = 0; kt < H_DIM; kt += 32) {
    // Stage A (gathered x rows): 128x32 fp32 -> bf16
#pragma unroll
    for (int p = 0; p < 4; p++) {
      int idx = p * 256 + tid;
      int r = idx >> 3, c4 = (idx & 7) * 4;
      int t = t_ids[r];
      float4 v = *(const float4*)(x + (size_t)t * H_DIM + kt + c4);
      us4 d; d.x = f2bf(v.x); d.y = f2bf(v.y); d.z = f2bf(v.z); d.w = f2bf(v.w);
      *(us4*)&As[r * 32 + c4] = d;
    }
    // Stage B1/B3: 64x32 fp32 -> bf16 each
#pragma unroll
    for (int p = 0; p < 2; p++) {
      int idx = p * 256 + tid;
      int r = idx >> 3, c4 = (idx & 7) * 4;
      float4 v = *(const float4*)(W1e + (size_t)r * H_DIM + kt + c4);
      us4 d; d.x = f2bf(v.x); d.y = f2bf(v.y); d.z = f2bf(v.z); d.w = f2bf(v.w);
      *(us4*)&B1s[r * 32 + c4] = d;
      float4 u = *(const float4*)(W3e + (size_t)r * H_DIM + kt + c4);
      us4 d3; d3.x = f2bf(u.x); d3.y = f2bf(u.y); d3.z = f2bf(u.z); d3.w = f2bf(u.w);
      *(us4*)&B3s[r * 32 + c4] = d3;
    }
    __syncthreads();

    bf16x8 a[4], b1[2], b3[2];
#pragma unroll
    for (int mi = 0; mi < 4; mi++)
      a[mi] = *(const bf16x8*)&As[(wm + mi * 16 + lr) * 32 + qk];
#pragma unroll
    for (int ni = 0; ni < 2; ni++) {
      b1[ni] = *(const bf16x8*)&B1s[(wn + ni * 16 + lr) * 32 + qk];
      b3[ni] = *(const bf16x8*)&B3s[(wn + ni * 16 + lr) * 32 + qk];
    }
#pragma unroll
    for (int mi = 0; mi < 4; mi++)
#pragma unroll
      for (int ni = 0; ni < 2; ni++) {
        acc1[mi][ni] = __builtin_amdgcn_mfma_f32_16x16x32_bf16(a[mi], b1[ni], acc1[mi][ni], 0, 0, 0);
        acc3[mi][ni] = __builtin_amdgcn_mfma_f32_16x16x32_bf16(a[mi], b3[ni], acc3[mi][ni], 0, 0, 0);
      }
    __syncthreads();
  }

  // Epilogue: g = silu(h1)*h3*w -> bf16 G[slot][ffn]
  const int be = base[e];
#pragma unroll
  for (int mi = 0; mi < 4; mi++)
#pragma unroll
    for (int ni = 0; ni < 2; ni++)
#pragma unroll
      for (int r = 0; r < 4; r++) {
        int row = wm + mi * 16 + (lane >> 4) * 4 + r;
        int col = wn + ni * 16 + lr;
        int i = m0 + row;
        if (i < ce) {
          float h1 = acc1[mi][ni][r];
          float h3 = acc3[mi][ni][r];
          float g  = h1 / (1.f + expf(-h1)) * h3 * w_lds[row];
          G[(size_t)(be + i) * FFN_D + n0 + col] = f2bf(g);
        }
      }
}

// ---------------- Kernel 4: grouped down-proj, scatter-add into out ----------------
// Tile: BM=128 (slots), BN=128 (h), BK=32 over FFN. 4 waves 2x2; wave tile 64x64.
__launch_bounds__(256)
__global__ void downproj_kernel(const unsigned short* __restrict__ G,
                                const float* __restrict__ W2,
                                const int* __restrict__ cnt,
                                const int* __restrict__ base,
                                const int* __restrict__ rows,
                                float* __restrict__ out) {
  const int e  = blockIdx.z;
  const int m0 = blockIdx.y * 128;
  const int n0 = blockIdx.x * 128;
  const int ce = cnt[e];
  if (m0 >= ce) return;
  const int be = base[e];

  __shared__ __align__(16) unsigned short As[128 * 32];
  __shared__ __align__(16) unsigned short Bs[128 * 32];

  const int tid  = threadIdx.x;
  const int lane = tid & 63;
  const int wid  = tid >> 6;
  const int wm   = (wid & 1) * 64;
  const int wn   = (wid >> 1) * 64;
  const int qk   = (lane >> 4) * 8;
  const int lr   = lane & 15;

  f32x4 acc[4][4];
#pragma unroll
  for (int mi = 0; mi < 4; mi++)
#pragma unroll
    for (int ni = 0; ni < 4; ni++) acc[mi][ni] = (f32x4)0.f;

  const float* W2e = W2 + (size_t)e * H_DIM * FFN_D + (size_t)n0 * FFN_D;

  for (int kt = 0; kt < FFN_D; kt += 32) {
    // Stage A: 128x32 bf16 straight copy (16B per thread per pass)
#pragma unroll
    for (int p = 0; p < 2; p++) {
      int idx = p * 256 + tid;
      int r = idx >> 2, c8 = (idx & 3) * 8;
      int i = m0 + r; if (i >= ce) i = ce - 1;  // clamp: stay inside G
      uint4 v = *(const uint4*)(G + (size_t)(be + i) * FFN_D + kt + c8);
      *(uint4*)&As[r * 32 + c8] = v;
    }
    // Stage B: 128x32 fp32 -> bf16
#pragma unroll
    for (int p = 0; p < 4; p++) {
      int idx = p * 256 + tid;
      int r = idx >> 3, c4 = (idx & 7) * 4;
      float4 v = *(const float4*)(W2e + (size_t)r * FFN_D + kt + c4);
      us4 d; d.x = f2bf(v.x); d.y = f2bf(v.y); d.z = f2bf(v.z); d.w = f2bf(v.w);
      *(us4*)&Bs[r * 32 + c4] = d;
    }
    __syncthreads();

    bf16x8 a[4], b[4];
#pragma unroll
    for (int mi = 0; mi < 4; mi++)
      a[mi] = *(const bf16x8*)&As[(wm + mi * 16 + lr) * 32 + qk];
#pragma unroll
    for (int ni = 0; ni < 4; ni++)
      b[ni] = *(const bf16x8*)&Bs[(wn + ni * 16 + lr) * 32 + qk];
#pragma unroll
    for (int mi = 0; mi < 4; mi++)
#pragma unroll
      for (int ni = 0; ni < 4; ni++)
        acc[mi][ni] = __builtin_amdgcn_mfma_f32_16x16x32_bf16(a[mi], b[ni], acc[mi][ni], 0, 0, 0);
    __syncthreads();
  }

#pragma unroll
  for (int mi = 0; mi < 4; mi++)
#pragma unroll
    for (int ni = 0; ni < 4; ni++)
#pragma unroll
      for (int r = 0; r < 4; r++) {
        int row = wm + mi * 16 + (lane >> 4) * 4 + r;
        int col = wn + ni * 16 + lr;
        int i = m0 + row;
        if (i < ce) {
          int t = rows[e * T_TOK + i];
          atomicAdd(&out[(size_t)t * H_DIM + n0 + col], acc[mi][ni][r]);
        }
      }
}

// ---------------- Launch ----------------
extern "C" void kernel_launch(void* const* d_in, const int* in_sizes, int n_in,
                              void* d_out, int out_size, void* d_ws, size_t ws_size,
                              hipStream_t stream) {
  (void)in_sizes; (void)n_in; (void)ws_size;
  const float* x    = (const float*)d_in[0];  // [T, H] (flattened [B,S,H])
  const float* Wg   = (const float*)d_in[1];  // [E, H]
  const float* W1   = (const float*)d_in[2];  // [E, FFN, H]
  const float* W2   = (const float*)d_in[3];  // [E, H, FFN]
  const float* W3   = (const float*)d_in[4];  // [E, FFN, H]
  const float* bias = (const float*)d_in[5];  // [E]
  float* out = (float*)d_out;

  char* ws = (char*)d_ws;
  int*   cnt  = (int*)(ws);                 // 8 ints (64B region, memset 0)
  int*   base = (int*)(ws + 64);            // 9 ints
  int*   rows = (int*)(ws + 512);           // E*T ints      = 131072 B
  float* wts  = (float*)(ws + 512 + 131072);// E*T floats    = 131072 B
  unsigned short* G = (unsigned short*)(ws + 512 + 2 * 131072); // 2T x FFN bf16 = 16 MB
  // total ws use ~16.3 MB

  hipMemsetAsync(cnt, 0, 64, stream);
  hipMemsetAsync(out, 0, (size_t)out_size * sizeof(float), stream);

  router_kernel<<<T_TOK / 4, 256, 0, stream>>>(x, Wg, bias, cnt, rows, wts);
  prefix_kernel<<<1, 64, 0, stream>>>(cnt, base);

  dim3 g2(FFN_D / 64, T_TOK / 128, NE);
  upproj_kernel<<<g2, 256, 0, stream>>>(x, W1, W3, cnt, base, rows, wts, G);

  dim3 g3(H_DIM / 128, T_TOK / 128, NE);
  downproj_kernel<<<g3, 256, 0, stream>>>(G, W2, cnt, base, rows, out);
}

// Round 2
// 506.135 us; speedup vs baseline: 1.2262x; 1.2262x over previous
//
#include <hip/hip_runtime.h>
#include <hip/hip_bf16.h>

// MoE top-2/8, T=4096, H=2048, FFN=1024.
// Fast path: router(+x->bf16) -> convert W1/W3 -> grouped upproj (global_load_lds)
//            -> convert W2 -> grouped downproj -> per-token combine.
// Fallback (small ws): round-1 verified kernels.

#define T_TOK 4096
#define H_DIM 2048
#define FFN_D 1024
#define NE    8

typedef __attribute__((ext_vector_type(8))) short          bf16x8;
typedef __attribute__((ext_vector_type(4))) float          f32x4;
typedef __attribute__((ext_vector_type(4))) unsigned short us4;

__device__ __forceinline__ unsigned short f2bf(float f) {
  unsigned u = __builtin_bit_cast(unsigned, f);
  u += 0x7fffu + ((u >> 16) & 1u);
  return (unsigned short)(u >> 16);
}
__device__ __forceinline__ float bf2f(unsigned short u) {
  return __builtin_bit_cast(float, ((unsigned)u) << 16);
}
// async 16B/lane global->LDS. LDS dst is wave-uniform base; HW scatters lane i to base+16*i.
__device__ __forceinline__ void async16(const void* g, void* l) {
  __builtin_amdgcn_global_load_lds((const __attribute__((address_space(1))) void*)g,
                                   (__attribute__((address_space(3))) void*)l, 16, 0, 0);
}

// ======================= shared: prefix over 8 counts =======================
__global__ void prefix_kernel(const int* __restrict__ cnt, int* __restrict__ base) {
  if (threadIdx.x == 0) {
    int s = 0;
    for (int e = 0; e < NE; e++) { base[e] = s; s += cnt[e]; }
    base[NE] = s;
  }
}

// ======================= FAST PATH =======================

// Router: one wave/token. Computes logits, top-2, per-expert compaction,
// token->slot map, and writes x as bf16 (Xb) while it has it in registers.
__global__ void router_fast(const float* __restrict__ x,
                            const float* __restrict__ Wg,
                            const float* __restrict__ bias,
                            int* __restrict__ cnt,
                            int* __restrict__ rows,
                            float* __restrict__ wts,
                            int* __restrict__ tok2slot,
                            unsigned short* __restrict__ Xb) {
  const int wv   = threadIdx.x >> 6;
  const int lane = threadIdx.x & 63;
  const int t    = blockIdx.x * 4 + wv;

  const float4* xr = (const float4*)(x + (size_t)t * H_DIM);
  us4*          xb = (us4*)(Xb + (size_t)t * H_DIM);

  float acc[NE];
#pragma unroll
  for (int e = 0; e < NE; e++) acc[e] = 0.f;

#pragma unroll
  for (int j = 0; j < 8; j++) {
    int i4 = j * 64 + lane;               // float4 index within row (512 total)
    float4 v = xr[i4];
    us4 d; d.x = f2bf(v.x); d.y = f2bf(v.y); d.z = f2bf(v.z); d.w = f2bf(v.w);
    xb[i4] = d;
#pragma unroll
    for (int e = 0; e < NE; e++) {
      float4 w = ((const float4*)(Wg + e * H_DIM))[i4];
      acc[e] += v.x * w.x + v.y * w.y + v.z * w.z + v.w * w.w;
    }
  }
#pragma unroll
  for (int e = 0; e < NE; e++) {
#pragma unroll
    for (int m = 32; m >= 1; m >>= 1) acc[e] += __shfl_xor(acc[e], m, 64);
  }

  if (lane == 0) {
    float sig[NE], sc[NE];
#pragma unroll
    for (int e = 0; e < NE; e++) {
      sig[e] = 1.f / (1.f + expf(-acc[e]));
      sc[e]  = sig[e] + bias[e];
    }
    int i1 = 0; float v1 = sc[0];
#pragma unroll
    for (int e = 1; e < NE; e++) if (sc[e] > v1) { v1 = sc[e]; i1 = e; }
    int i2 = -1; float v2 = -1e30f;
#pragma unroll
    for (int e = 0; e < NE; e++) if (e != i1 && sc[e] > v2) { v2 = sc[e]; i2 = e; }

    float w1 = sig[i1], w2 = sig[i2];
    float s = w1 + w2; w1 /= s; w2 /= s;

    int p1 = atomicAdd(&cnt[i1], 1);
    rows[i1 * T_TOK + p1] = t;
    wts [i1 * T_TOK + p1] = w1;
    int p2 = atomicAdd(&cnt[i2], 1);
    rows[i2 * T_TOK + p2] = t;
    wts [i2 * T_TOK + p2] = w2;
    tok2slot[2 * t]     = (i1 << 12) | p1;
    tok2slot[2 * t + 1] = (i2 << 12) | p2;
  }
}

// fp32 -> bf16, 1 float4 per thread. n_elems must be divisible by 1024.
__global__ void convert_kernel(const float* __restrict__ s, unsigned short* __restrict__ d) {
  size_t i = (size_t)blockIdx.x * 256 + threadIdx.x;
  float4 v = ((const float4*)s)[i];
  us4 o; o.x = f2bf(v.x); o.y = f2bf(v.y); o.z = f2bf(v.z); o.w = f2bf(v.w);
  ((us4*)d)[i] = o;
}

// Up-proj: BM=128 slots x BN=64 ffn, BK=32; 4 waves 2x2; wave tile 64x32 for BOTH W1 and W3.
__launch_bounds__(256)
__global__ void upproj_fast(const unsigned short* __restrict__ Xb,
                            const unsigned short* __restrict__ W1b,
                            const unsigned short* __restrict__ W3b,
                            const int* __restrict__ cnt,
                            const int* __restrict__ base,
                            const int* __restrict__ rows,
                            const float* __restrict__ wts,
                            unsigned short* __restrict__ G) {
  const int e  = blockIdx.z;
  const int m0 = blockIdx.y * 128;
  const int n0 = blockIdx.x * 64;
  const int ce = cnt[e];
  if (m0 >= ce) return;

  __shared__ __align__(16) unsigned short As [128 * 32];
  __shared__ __align__(16) unsigned short B1s[64 * 32];
  __shared__ __align__(16) unsigned short B3s[64 * 32];
  __shared__ int   t_ids[128];
  __shared__ float w_lds[128];

  const int tid = threadIdx.x;
  if (tid < 128) {
    int i = m0 + tid;
    if (i < ce) { t_ids[tid] = rows[e * T_TOK + i]; w_lds[tid] = wts[e * T_TOK + i]; }
    else        { t_ids[tid] = 0;                   w_lds[tid] = 0.f; }
  }
  __syncthreads();

  const int lane = tid & 63;
  const int wv   = tid >> 6;

  // DMA source pointers (per lane): 16 rows per wave per call, 4 lanes per 64B row slice
  const unsigned short* gA[2];
#pragma unroll
  for (int c = 0; c < 2; c++) {
    int r = wv * 32 + c * 16 + (lane >> 2);
    gA[c] = Xb + (size_t)t_ids[r] * H_DIM + (lane & 3) * 8;
  }
  const size_t wrow = (size_t)(n0 + wv * 16 + (lane >> 2));
  const unsigned short* gB1 = W1b + (size_t)e * FFN_D * H_DIM + wrow * H_DIM + (lane & 3) * 8;
  const unsigned short* gB3 = W3b + (size_t)e * FFN_D * H_DIM + wrow * H_DIM + (lane & 3) * 8;
  // wave-uniform LDS segment bases
  unsigned short* lA0 = &As [(wv * 32 + 0)  * 32];
  unsigned short* lA1 = &As [(wv * 32 + 16) * 32];
  unsigned short* lB1 = &B1s[(wv * 16) * 32];
  unsigned short* lB3 = &B3s[(wv * 16) * 32];

  const int wm = (wv & 1) * 64;
  const int wn = (wv >> 1) * 32;
  const int qk = (lane >> 4) * 8;
  const int lr = lane & 15;

  f32x4 acc1[4][2], acc3[4][2];
#pragma unroll
  for (int mi = 0; mi < 4; mi++)
#pragma unroll
    for (int ni = 0; ni < 2; ni++) { acc1[mi][ni] = (f32x4)0.f; acc3[mi][ni] = (f32x4)0.f; }

  for (int kt = 0; kt < H_DIM; kt += 32) {
    async16(gA[0] + kt, lA0);
    async16(gA[1] + kt, lA1);
    async16(gB1 + kt,   lB1);
    async16(gB3 + kt,   lB3);
    __syncthreads();

    bf16x8 a[4], b1[2], b3[2];
#pragma unroll
    for (int mi = 0; mi < 4; mi++)
      a[mi] = *(const bf16x8*)&As[(wm + mi * 16 + lr) * 32 + qk];
#pragma unroll
    for (int ni = 0; ni < 2; ni++) {
      b1[ni] = *(const bf16x8*)&B1s[(wn + ni * 16 + lr) * 32 + qk];
      b3[ni] = *(const bf16x8*)&B3s[(wn + ni * 16 + lr) * 32 + qk];
    }
#pragma unroll
    for (int mi = 0; mi < 4; mi++)
#pragma unroll
      for (int ni = 0; ni < 2; ni++) {
        acc1[mi][ni] = __builtin_amdgcn_mfma_f32_16x16x32_bf16(a[mi], b1[ni], acc1[mi][ni], 0, 0, 0);
        acc3[mi][ni] = __builtin_amdgcn_mfma_f32_16x16x32_bf16(a[mi], b3[ni], acc3[mi][ni], 0, 0, 0);
      }
    __syncthreads();
  }

  const int be = base[e];
#pragma unroll
  for (int mi = 0; mi < 4; mi++)
#pragma unroll
    for (int ni = 0; ni < 2; ni++)
#pragma unroll
      for (int r = 0; r < 4; r++) {
        int row = wm + mi * 16 + (lane >> 4) * 4 + r;
        int col = wn + ni * 16 + lr;
        int i = m0 + row;
        if (i < ce) {
          float h1 = acc1[mi][ni][r];
          float h3 = acc3[mi][ni][r];
          float g  = h1 / (1.f + expf(-h1)) * h3 * w_lds[row];
          G[(size_t)(be + i) * FFN_D + n0 + col] = f2bf(g);
        }
      }
}

// Down-proj: BM=128 slots x BN=128 h, BK=32 over FFN; writes bf16 slot rows Gd.
__launch_bounds__(256)
__global__ void downproj_fast(const unsigned short* __restrict__ G,
                              const unsigned short* __restrict__ W2b,
                              const int* __restrict__ cnt,
                              const int* __restrict__ base,
                              unsigned short* __restrict__ Gd) {
  const int e  = blockIdx.z;
  const int m0 = blockIdx.y * 128;
  const int n0 = blockIdx.x * 128;
  const int ce = cnt[e];
  if (m0 >= ce) return;
  const int be = base[e];

  __shared__ __align__(16) unsigned short As[128 * 32];
  __shared__ __align__(16) unsigned short Bs[128 * 32];

  const int tid  = threadIdx.x;
  const int lane = tid & 63;
  const int wv   = tid >> 6;

  const unsigned short* gA[2];
  const unsigned short* gB[2];
#pragma unroll
  for (int c = 0; c < 2; c++) {
    int r = m0 + wv * 32 + c * 16 + (lane >> 2);
    if (r >= ce) r = ce - 1;                       // clamp inside valid slots
    gA[c] = G + (size_t)(be + r) * FFN_D + (lane & 3) * 8;
    int rb = wv * 32 + c * 16 + (lane >> 2);
    gB[c] = W2b + (size_t)e * H_DIM * FFN_D + (size_t)(n0 + rb) * FFN_D + (lane & 3) * 8;
  }
  unsigned short* lA[2] = { &As[(wv * 32 + 0) * 32], &As[(wv * 32 + 16) * 32] };
  unsigned short* lB[2] = { &Bs[(wv * 32 + 0) * 32], &Bs[(wv * 32 + 16) * 32] };

  const int wm = (wv & 1) * 64;
  const int wn = (wv >> 1) * 64;
  const int qk = (lane >> 4) * 8;
  const int lr = lane & 15;

  f32x4 acc[4][4];
#pragma unroll
  for (int mi = 0; mi < 4; mi++)
#pragma unroll
    for (int ni = 0; ni < 4; ni++) acc[mi][ni] = (f32x4)0.f;

  for (int kt = 0; kt < FFN_D; kt += 32) {
    async16(gA[0] + kt, lA[0]);
    async16(gA[1] + kt, lA[1]);
    async16(gB[0] + kt, lB[0]);
    async16(gB[1] + kt, lB[1]);
    __syncthreads();

    bf16x8 a[4], b[4];
#pragma unroll
    for (int mi = 0; mi < 4; mi++)
      a[mi] = *(const bf16x8*)&As[(wm + mi * 16 + lr) * 32 + qk];
#pragma unroll
    for (int ni = 0; ni < 4; ni++)
      b[ni] = *(const bf16x8*)&Bs[(wn + ni * 16 + lr) * 32 + qk];
#pragma unroll
    for (int mi = 0; mi < 4; mi++)
#pragma unroll
      for (int ni = 0; ni < 4; ni++)
        acc[mi][ni] = __builtin_amdgcn_mfma_f32_16x16x32_bf16(a[mi], b[ni], acc[mi][ni], 0, 0, 0);
    __syncthreads();
  }

#pragma unroll
  for (int mi = 0; mi < 4; mi++)
#pragma unroll
    for (int ni = 0; ni < 4; ni++)
#pragma unroll
      for (int r = 0; r < 4; r++) {
        int row = wm + mi * 16 + (lane >> 4) * 4 + r;
        int col = wn + ni * 16 + lr;
        int i = m0 + row;
        if (i < ce)
          Gd[(size_t)(be + i) * H_DIM + n0 + col] = f2bf(acc[mi][ni][r]);
      }
}

// Combine: out[t] = Gd[slot1(t)] + Gd[slot2(t)], one block per token.
__global__ void combine_kernel(const unsigned short* __restrict__ Gd,
                               const int* __restrict__ base,
                               const int* __restrict__ tok2slot,
                               float* __restrict__ out) {
  const int t = blockIdx.x;
  const int v1 = tok2slot[2 * t], v2 = tok2slot[2 * t + 1];
  const int s1 = base[v1 >> 12] + (v1 & 4095);
  const int s2 = base[v2 >> 12] + (v2 & 4095);
  const us4* r1 = (const us4*)(Gd + (size_t)s1 * H_DIM);
  const us4* r2 = (const us4*)(Gd + (size_t)s2 * H_DIM);
  float4* o = (float4*)(out + (size_t)t * H_DIM);
#pragma unroll
  for (int j = 0; j < 2; j++) {
    int i = j * 256 + threadIdx.x;       // 512 us4 groups per row
    us4 a = r1[i], b = r2[i];
    float4 r;
    r.x = bf2f(a.x) + bf2f(b.x);
    r.y = bf2f(a.y) + bf2f(b.y);
    r.z = bf2f(a.z) + bf2f(b.z);
    r.w = bf2f(a.w) + bf2f(b.w);
    o[i] = r;
  }
}

// ======================= FALLBACK (round-1, verified) =======================
__global__ void router_v1(const float* __restrict__ x, const float* __restrict__ Wg,
                          const float* __restrict__ bias, int* __restrict__ cnt,
                          int* __restrict__ rows, float* __restrict__ wts) {
  const int wid = threadIdx.x >> 6, lane = threadIdx.x & 63;
  const int t = blockIdx.x * 4 + wid;
  float acc[NE];
#pragma unroll
  for (int e = 0; e < NE; e++) acc[e] = 0.f;
  const float* xr = x + (size_t)t * H_DIM;
  for (int h = lane; h < H_DIM; h += 64) {
    float xv = xr[h];
#pragma unroll
    for (int e = 0; e < NE; e++) acc[e] += xv * Wg[e * H_DIM + h];
  }
#pragma unroll
  for (int e = 0; e < NE; e++)
#pragma unroll
    for (int m = 32; m >= 1; m >>= 1) acc[e] += __shfl_xor(acc[e], m, 64);
  if (lane == 0) {
    float sig[NE], sc[NE];
#pragma unroll
    for (int e = 0; e < NE; e++) { sig[e] = 1.f / (1.f + expf(-acc[e])); sc[e] = sig[e] + bias[e]; }
    int i1 = 0; float v1 = sc[0];
#pragma unroll
    for (int e = 1; e < NE; e++) if (sc[e] > v1) { v1 = sc[e]; i1 = e; }
    int i2 = -1; float v2 = -1e30f;
#pragma unroll
    for (int e = 0; e < NE; e++) if (e != i1 && sc[e] > v2) { v2 = sc[e]; i2 = e; }
    float w1 = sig[i1], w2 = sig[i2], s = w1 + w2; w1 /= s; w2 /= s;
    int p1 = atomicAdd(&cnt[i1], 1); rows[i1 * T_TOK + p1] = t; wts[i1 * T_TOK + p1] = w1;
    int p2 = atomicAdd(&cnt[i2], 1); rows[i2 * T_TOK + p2] = t; wts[i2 * T_TOK + p2] = w2;
  }
}

__launch_bounds__(256)
__global__ void upproj_v1(const float* __restrict__ x, const float* __restrict__ W1,
                          const float* __restrict__ W3, const int* __restrict__ cnt,
                          const int* __restrict__ base, const int* __restrict__ rows,
                          const float* __restrict__ wts, unsigned short* __restrict__ G) {
  const int e = blockIdx.z, m0 = blockIdx.y * 128, n0 = blockIdx.x * 64;
  const int ce = cnt[e];
  if (m0 >= ce) return;
  __shared__ __align__(16) unsigned short As[128 * 32], B1s[64 * 32], B3s[64 * 32];
  __shared__ int t_ids[128]; __shared__ float w_lds[128];
  const int tid = threadIdx.x;
  if (tid < 128) {
    int i = m0 + tid;
    if (i < ce) { t_ids[tid] = rows[e * T_TOK + i]; w_lds[tid] = wts[e * T_TOK + i]; }
    else { t_ids[tid] = 0; w_lds[tid] = 0.f; }
  }
  __syncthreads();
  const float* W1e = W1 + (size_t)e * FFN_D * H_DIM + (size_t)n0 * H_DIM;
  const float* W3e = W3 + (size_t)e * FFN_D * H_DIM + (size_t)n0 * H_DIM;
  const int lane = tid & 63, wid = tid >> 6;
  const int wm = (wid & 1) * 64, wn = (wid >> 1) * 32;
  const int qk = (lane >> 4) * 8, lr = lane & 15;
  f32x4 acc1[4][2], acc3[4][2];
#pragma unroll
  for (int mi = 0; mi < 4; mi++)
#pragma unroll
    for (int ni = 0; ni < 2; ni++) { acc1[mi][ni] = (f32x4)0.f; acc3[mi][ni] = (f32x4)0.f; }
  for (int kt = 0; kt < H_DIM; kt += 32) {
#pragma unroll
    for (int p = 0; p < 4; p++) {
      int idx = p * 256 + tid, r = idx >> 3, c4 = (idx & 7) * 4;
      float4 v = *(const float4*)(x + (size_t)t_ids[r] * H_DIM + kt + c4);
      us4 d; d.x = f2bf(v.x); d.y = f2bf(v.y); d.z = f2bf(v.z); d.w = f2bf(v.w);
      *(us4*)&As[r * 32 + c4] = d;
    }
#pragma unroll
    for (int p = 0; p < 2; p++) {
      int idx = p * 256 + tid, r = idx >> 3, c4 = (idx & 7) * 4;
      float4 v = *(const float4*)(W1e + (size_t)r * H_DIM + kt + c4);
      us4 d; d.x = f2bf(v.x); d.y = f2bf(v.y); d.z = f2bf(v.z); d.w = f2bf(v.w);
      *(us4*)&B1s[r * 32 + c4] = d;
      float4 u = *(const float4*)(W3e + (size_t)r * H_DIM + kt + c4);
      us4 d3; d3.x = f2bf(u.x); d3.y = f2bf(u.y); d3.z = f2bf(u.z); d3.w = f2bf(u.w);
      *(us4*)&B3s[r * 32 + c4] = d3;
    }
    __syncthreads();
    bf16x8 a[4], b1[2], b3[2];
#pragma unroll
    for (int mi = 0; mi < 4; mi++) a[mi] = *(const bf16x8*)&As[(wm + mi * 16 + lr) * 32 + qk];
#pragma unroll
    for (int ni = 0; ni < 2; ni++) {
      b1[ni] = *(const bf16x8*)&B1s[(wn + ni * 16 + lr) * 32 + qk];
      b3[ni] = *(const bf16x8*)&B3s[(wn + ni * 16 + lr) * 32 + qk];
    }
#pragma unroll
    for (int mi = 0; mi < 4; mi++)
#pragma unroll
      for (int ni = 0; ni < 2; ni++) {
        acc1[mi][ni] = __builtin_amdgcn_mfma_f32_16x16x32_bf16(a[mi], b1[ni], acc1[mi][ni], 0, 0, 0);
        acc3[mi][ni] = __builtin_amdgcn_mfma_f32_16x16x32_bf16(a[mi], b3[ni], acc3[mi][ni], 0, 0, 0);
      }
    __syncthreads();
  }
  const int be = base[e];
#pragma unroll
  for (int mi = 0; mi < 4; mi++)
#pragma unroll
    for (int ni = 0; ni < 2; ni++)
#pragma unroll
      for (int r = 0; r < 4; r++) {
        int row = wm + mi * 16 + (lane >> 4) * 4 + r, col = wn + ni * 16 + lr, i = m0 + row;
        if (i < ce) {
          float h1 = acc1[mi][ni][r], h3 = acc3[mi][ni][r];
          float g = h1 / (1.f + expf(-h1)) * h3 * w_lds[row];
          G[(size_t)(be + i) * FFN_D + n0 + col] = f2bf(g);
        }
      }
}

__launch_bounds__(256)
__global__ void downproj_v1(const unsigned short* __restrict__ G, const float* __restrict__ W2,
                            const int* __restrict__ cnt, const int* __restrict__ base,
                            const int* __restrict__ rows, float* __restrict__ out) {
  const int e = blockIdx.z, m0 = blockIdx.y * 128, n0 = blockIdx.x * 128;
  const int ce = cnt[e];
  if (m0 >= ce) return;
  const int be = base[e];
  __shared__ __align__(16) unsigned short As[128 * 32], Bs[128 * 32];
  const int tid = threadIdx.x, lane = tid & 63, wid = tid >> 6;
  const int wm = (wid & 1) * 64, wn = (wid >> 1) * 64;
  const int qk = (lane >> 4) * 8, lr = lane & 15;
  f32x4 acc[4][4];
#pragma unroll
  for (int mi = 0; mi < 4; mi++)
#pragma unroll
    for (int ni = 0; ni < 4; ni++) acc[mi][ni] = (f32x4)0.f;
  const float* W2e = W2 + (size_t)e * H_DIM * FFN_D + (size_t)n0 * FFN_D;
  for (int kt = 0; kt < FFN_D; kt += 32) {
#pragma unroll
    for (int p = 0; p < 2; p++) {
      int idx = p * 256 + tid, r = idx >> 2, c8 = (idx & 3) * 8;
      int i = m0 + r; if (i >= ce) i = ce - 1;
      uint4 v = *(const uint4*)(G + (size_t)(be + i) * FFN_D + kt + c8);
      *(uint4*)&As[r * 32 + c8] = v;
    }
#pragma unroll
    for (int p = 0; p < 4; p++) {
      int idx = p * 256 + tid, r = idx >> 3, c4 = (idx & 7) * 4;
      float4 v = *(const float4*)(W2e + (size_t)r * FFN_D + kt + c4);
      us4 d; d.x = f2bf(v.x); d.y = f2bf(v.y); d.z = f2bf(v.z); d.w = f2bf(v.w);
      *(us4*)&Bs[r * 32 + c4] = d;
    }
    __syncthreads();
    bf16x8 a[4], b[4];
#pragma unroll
    for (int mi = 0; mi < 4; mi++) a[mi] = *(const bf16x8*)&As[(wm + mi * 16 + lr) * 32 + qk];
#pragma unroll
    for (int ni = 0; ni < 4; ni++) b[ni] = *(const bf16x8*)&Bs[(wn + ni * 16 + lr) * 32 + qk];
#pragma unroll
    for (int mi = 0; mi < 4; mi++)
#pragma unroll
      for (int ni = 0; ni < 4; ni++)
        acc[mi][ni] = __builtin_amdgcn_mfma_f32_16x16x32_bf16(a[mi], b[ni], acc[mi][ni], 0, 0, 0);
    __syncthreads();
  }
#pragma unroll
  for (int mi = 0; mi < 4; mi++)
#pragma unroll
    for (int ni = 0; ni < 4; ni++)
#pragma unroll
      for (int r = 0; r < 4; r++) {
        int row = wm + mi * 16 + (lane >> 4) * 4 + r, col = wn + ni * 16 + lr, i = m0 + row;
        if (i < ce) {
          int t = rows[e * T_TOK + i];
          atomicAdd(&out[(size_t)t * H_DIM + n0 + col], acc[mi][ni][r]);
        }
      }
}

// ======================= Launch =======================
extern "C" void kernel_launch(void* const* d_in, const int* in_sizes, int n_in,
                              void* d_out, int out_size, void* d_ws, size_t ws_size,
                              hipStream_t stream) {
  (void)in_sizes; (void)n_in;
  const float* x    = (const float*)d_in[0];
  const float* Wg   = (const float*)d_in[1];
  const float* W1   = (const float*)d_in[2];
  const float* W2   = (const float*)d_in[3];
  const float* W3   = (const float*)d_in[4];
  const float* bias = (const float*)d_in[5];
  float* out = (float*)d_out;

  char* ws = (char*)d_ws;
  // fast-path layout
  const size_t OFF_CNT  = 0;
  const size_t OFF_BASE = 64;
  const size_t OFF_T2S  = 1024;                      // 32 KB
  const size_t OFF_ROWS = 65536;                     // 128 KB
  const size_t OFF_WTS  = OFF_ROWS + 131072;         // 128 KB
  const size_t OFF_XB   = 1048576;                   // 16 MB
  const size_t OFF_W1B  = OFF_XB + 16777216;         // 32 MB (Gd aliases)
  const size_t OFF_W3B  = OFF_W1B + 33554432;        // 32 MB (W2b aliases)
  const size_t OFF_G    = OFF_W3B + 33554432;        // 16 MB
  const size_t REQ      = OFF_G + 16777216;          // ~97 MB

  int*   cnt  = (int*)(ws + OFF_CNT);
  int*   base = (int*)(ws + OFF_BASE);
  int*   rows = (int*)(ws + OFF_ROWS);
  float* wts  = (float*)(ws + OFF_WTS);

  if (ws_size >= REQ) {
    int* t2s = (int*)(ws + OFF_T2S);
    unsigned short* Xb  = (unsigned short*)(ws + OFF_XB);
    unsigned short* W1b = (unsigned short*)(ws + OFF_W1B);
    unsigned short* W3b = (unsigned short*)(ws + OFF_W3B);
    unsigned short* W2b = (unsigned short*)(ws + OFF_W3B);  // alias: W3b dead after upproj
    unsigned short* Gd  = (unsigned short*)(ws + OFF_W1B);  // alias: W1b dead after upproj
    unsigned short* G   = (unsigned short*)(ws + OFF_G);

    hipMemsetAsync(cnt, 0, 64, stream);
    router_fast<<<T_TOK / 4, 256, 0, stream>>>(x, Wg, bias, cnt, rows, wts, t2s, Xb);
    prefix_kernel<<<1, 64, 0, stream>>>(cnt, base);
    const int CONV_BLOCKS = (NE * FFN_D * H_DIM) / 1024;   // 16384
    convert_kernel<<<CONV_BLOCKS, 256, 0, stream>>>(W1, W1b);
    convert_kernel<<<CONV_BLOCKS, 256, 0, stream>>>(W3, W3b);
    dim3 g2(FFN_D / 64, T_TOK / 128, NE);
    upproj_fast<<<g2, 256, 0, stream>>>(Xb, W1b, W3b, cnt, base, rows, wts, G);
    convert_kernel<<<CONV_BLOCKS, 256, 0, stream>>>(W2, W2b);
    dim3 g3(H_DIM / 128, T_TOK / 128, NE);
    downproj_fast<<<g3, 256, 0, stream>>>(G, W2b, cnt, base, Gd);
    combine_kernel<<<T_TOK, 256, 0, stream>>>(Gd, base, t2s, out);
  } else {
    // round-1 layout
    unsigned short* G = (unsigned short*)(ws + 512 + 2 * 131072);
    int*   rowsv = (int*)(ws + 512);
    float* wtsv  = (float*)(ws + 512 + 131072);
    hipMemsetAsync(cnt, 0, 64, stream);
    hipMemsetAsync(out, 0, (size_t)out_size * sizeof(float), stream);
    router_v1<<<T_TOK / 4, 256, 0, stream>>>(x, Wg, bias, cnt, rowsv, wtsv);
    prefix_kernel<<<1, 64, 0, stream>>>(cnt, base);
    dim3 g2(FFN_D / 64, T_TOK / 128, NE);
    upproj_v1<<<g2, 256, 0, stream>>>(x, W1, W3, cnt, base, rowsv, wtsv, G);
    dim3 g3(H_DIM / 128, T_TOK / 128, NE);
    downproj_v1<<<g3, 256, 0, stream>>>(G, W2, cnt, base, rowsv, out);
  }
}

// Round 3
// 465.896 us; speedup vs baseline: 1.3321x; 1.0864x over previous
//
#include <hip/hip_runtime.h>
#include <hip/hip_bf16.h>

// MoE top-2/8, T=4096, H=2048, FFN=1024.
// router (no atomics, +x->bf16) -> compact (1 block, ballot prefix) ->
// convert W1+W3 -> upproj (BK=64, global_load_lds) -> convert W2 ->
// downproj (BK=64) -> combine.

#define T_TOK 4096
#define H_DIM 2048
#define FFN_D 1024
#define NE    8

typedef __attribute__((ext_vector_type(8))) short          bf16x8;
typedef __attribute__((ext_vector_type(4))) float          f32x4;
typedef __attribute__((ext_vector_type(4))) unsigned short us4;

__device__ __forceinline__ unsigned short f2bf(float f) {
  unsigned u = __builtin_bit_cast(unsigned, f);
  u += 0x7fffu + ((u >> 16) & 1u);
  return (unsigned short)(u >> 16);
}
__device__ __forceinline__ float bf2f(unsigned short u) {
  return __builtin_bit_cast(float, ((unsigned)u) << 16);
}
__device__ __forceinline__ void async16(const void* g, void* l) {
  __builtin_amdgcn_global_load_lds((const __attribute__((address_space(1))) void*)g,
                                   (__attribute__((address_space(3))) void*)l, 16, 0, 0);
}

// ---------------- Router: wave/token, NO atomics. Writes epair/wpair + bf16 x. ----
__global__ void router2_kernel(const float* __restrict__ x,
                               const float* __restrict__ Wg,
                               const float* __restrict__ bias,
                               unsigned* __restrict__ epair,
                               float* __restrict__ wpair,
                               unsigned short* __restrict__ Xb) {
  const int wv   = threadIdx.x >> 6;
  const int lane = threadIdx.x & 63;
  const int t    = blockIdx.x * 4 + wv;

  const float4* xr = (const float4*)(x + (size_t)t * H_DIM);
  us4*          xb = (us4*)(Xb + (size_t)t * H_DIM);

  float acc[NE];
#pragma unroll
  for (int e = 0; e < NE; e++) acc[e] = 0.f;

#pragma unroll
  for (int j = 0; j < 8; j++) {
    int i4 = j * 64 + lane;
    float4 v = xr[i4];
    us4 d; d.x = f2bf(v.x); d.y = f2bf(v.y); d.z = f2bf(v.z); d.w = f2bf(v.w);
    xb[i4] = d;
#pragma unroll
    for (int e = 0; e < NE; e++) {
      float4 w = ((const float4*)(Wg + e * H_DIM))[i4];
      acc[e] += v.x * w.x + v.y * w.y + v.z * w.z + v.w * w.w;
    }
  }
#pragma unroll
  for (int e = 0; e < NE; e++) {
#pragma unroll
    for (int m = 32; m >= 1; m >>= 1) acc[e] += __shfl_xor(acc[e], m, 64);
  }

  if (lane == 0) {
    float sig[NE], sc[NE];
#pragma unroll
    for (int e = 0; e < NE; e++) {
      sig[e] = 1.f / (1.f + expf(-acc[e]));
      sc[e]  = sig[e] + bias[e];
    }
    int i1 = 0; float v1 = sc[0];
#pragma unroll
    for (int e = 1; e < NE; e++) if (sc[e] > v1) { v1 = sc[e]; i1 = e; }
    int i2 = -1; float v2 = -1e30f;
#pragma unroll
    for (int e = 0; e < NE; e++) if (e != i1 && sc[e] > v2) { v2 = sc[e]; i2 = e; }
    float w1 = sig[i1], w2 = sig[i2];
    float s = w1 + w2;
    epair[t] = (unsigned)i1 | ((unsigned)i2 << 8);
    wpair[2 * t]     = w1 / s;
    wpair[2 * t + 1] = w2 / s;
  }
}

// ---------------- Compaction: ONE block, 512 thr = 8 waves, wave e scans all tokens. ----
__global__ void compact_kernel(const unsigned* __restrict__ epair,
                               const float* __restrict__ wpair,
                               int* __restrict__ cnt,
                               int* __restrict__ base,
                               int* __restrict__ rows,
                               float* __restrict__ wts,
                               int* __restrict__ t2s) {
  const int e    = threadIdx.x >> 6;
  const int lane = threadIdx.x & 63;
  const unsigned long long ltmask = ((unsigned long long)1 << lane) - 1;
  __shared__ int cnts[NE];

  int count = 0;
  for (int c = 0; c < T_TOK; c += 64) {
    int t = c + lane;
    unsigned ep = epair[t];
    bool m1 = ((ep & 255u) == (unsigned)e);
    bool m2 = (((ep >> 8) & 255u) == (unsigned)e);
    unsigned long long b1 = __ballot(m1);
    if (m1) {
      int p = count + __popcll(b1 & ltmask);
      rows[e * T_TOK + p] = t;
      wts [e * T_TOK + p] = wpair[2 * t];
      t2s[2 * t] = (e << 12) | p;
    }
    count += __popcll(b1);
    unsigned long long b2 = __ballot(m2);
    if (m2) {
      int p = count + __popcll(b2 & ltmask);
      rows[e * T_TOK + p] = t;
      wts [e * T_TOK + p] = wpair[2 * t + 1];
      t2s[2 * t + 1] = (e << 12) | p;
    }
    count += __popcll(b2);
  }
  if (lane == 0) { cnts[e] = count; cnt[e] = count; }
  __syncthreads();
  if (threadIdx.x == 0) {
    int s = 0;
    for (int i = 0; i < NE; i++) { base[i] = s; s += cnts[i]; }
    base[NE] = s;
  }
}

// ---------------- Converters ----------------
__global__ void convert2_kernel(const float* __restrict__ a, unsigned short* __restrict__ da,
                                const float* __restrict__ b, unsigned short* __restrict__ db) {
  const size_t N4 = (size_t)NE * FFN_D * H_DIM / 4;
  size_t i = (size_t)blockIdx.x * 256 + threadIdx.x;
  const float* s; unsigned short* d;
  if (i < N4) { s = a; d = da; } else { s = b; d = db; i -= N4; }
  float4 v = ((const float4*)s)[i];
  us4 o; o.x = f2bf(v.x); o.y = f2bf(v.y); o.z = f2bf(v.z); o.w = f2bf(v.w);
  ((us4*)d)[i] = o;
}
__global__ void convert_kernel(const float* __restrict__ s, unsigned short* __restrict__ d) {
  size_t i = (size_t)blockIdx.x * 256 + threadIdx.x;
  float4 v = ((const float4*)s)[i];
  us4 o; o.x = f2bf(v.x); o.y = f2bf(v.y); o.z = f2bf(v.z); o.w = f2bf(v.w);
  ((us4*)d)[i] = o;
}

// ---------------- Up-proj: BM=128, BN=64(x2 mats), BK=64 (two 32-elem half panels) ----
__launch_bounds__(256)
__global__ void upproj_fast(const unsigned short* __restrict__ Xb,
                            const unsigned short* __restrict__ W1b,
                            const unsigned short* __restrict__ W3b,
                            const int* __restrict__ cnt,
                            const int* __restrict__ base,
                            const int* __restrict__ rows,
                            const float* __restrict__ wts,
                            unsigned short* __restrict__ G) {
  const int e  = blockIdx.z;
  const int m0 = blockIdx.y * 128;
  const int n0 = blockIdx.x * 64;
  const int ce = cnt[e];
  if (m0 >= ce) return;

  // half-panel layout: [h][row][32], row stride 64B (same bank profile as BK=32)
  __shared__ __align__(16) unsigned short As [2 * 128 * 32];
  __shared__ __align__(16) unsigned short B1s[2 * 64 * 32];
  __shared__ __align__(16) unsigned short B3s[2 * 64 * 32];
  __shared__ int   t_ids[128];
  __shared__ float w_lds[128];

  const int tid = threadIdx.x;
  if (tid < 128) {
    int i = m0 + tid;
    if (i < ce) { t_ids[tid] = rows[e * T_TOK + i]; w_lds[tid] = wts[e * T_TOK + i]; }
    else        { t_ids[tid] = 0;                   w_lds[tid] = 0.f; }
  }
  __syncthreads();

  const int lane = tid & 63;
  const int wv   = tid >> 6;

  // per-lane DMA sources: 16 rows per call, 4 lanes x 16B per row-half
  const unsigned short* gA[2];
#pragma unroll
  for (int c = 0; c < 2; c++) {
    int r = wv * 32 + c * 16 + (lane >> 2);
    gA[c] = Xb + (size_t)t_ids[r] * H_DIM + (lane & 3) * 8;
  }
  const size_t wrow = (size_t)(n0 + wv * 16 + (lane >> 2));
  const unsigned short* gB1 = W1b + (size_t)e * FFN_D * H_DIM + wrow * H_DIM + (lane & 3) * 8;
  const unsigned short* gB3 = W3b + (size_t)e * FFN_D * H_DIM + wrow * H_DIM + (lane & 3) * 8;

  const int wm = (wv & 1) * 64;
  const int wn = (wv >> 1) * 32;
  const int qk = (lane >> 4) * 8;
  const int lr = lane & 15;

  f32x4 acc1[4][2], acc3[4][2];
#pragma unroll
  for (int mi = 0; mi < 4; mi++)
#pragma unroll
    for (int ni = 0; ni < 2; ni++) { acc1[mi][ni] = (f32x4)0.f; acc3[mi][ni] = (f32x4)0.f; }

  for (int kt = 0; kt < H_DIM; kt += 64) {
#pragma unroll
    for (int h = 0; h < 2; h++) {
      async16(gA[0] + kt + h * 32, &As [h * 4096 + (wv * 32 + 0)  * 32]);
      async16(gA[1] + kt + h * 32, &As [h * 4096 + (wv * 32 + 16) * 32]);
      async16(gB1   + kt + h * 32, &B1s[h * 2048 + (wv * 16) * 32]);
      async16(gB3   + kt + h * 32, &B3s[h * 2048 + (wv * 16) * 32]);
    }
    __syncthreads();

#pragma unroll
    for (int h = 0; h < 2; h++) {
      bf16x8 a[4], b1[2], b3[2];
#pragma unroll
      for (int mi = 0; mi < 4; mi++)
        a[mi] = *(const bf16x8*)&As[h * 4096 + (wm + mi * 16 + lr) * 32 + qk];
#pragma unroll
      for (int ni = 0; ni < 2; ni++) {
        b1[ni] = *(const bf16x8*)&B1s[h * 2048 + (wn + ni * 16 + lr) * 32 + qk];
        b3[ni] = *(const bf16x8*)&B3s[h * 2048 + (wn + ni * 16 + lr) * 32 + qk];
      }
#pragma unroll
      for (int mi = 0; mi < 4; mi++)
#pragma unroll
        for (int ni = 0; ni < 2; ni++) {
          acc1[mi][ni] = __builtin_amdgcn_mfma_f32_16x16x32_bf16(a[mi], b1[ni], acc1[mi][ni], 0, 0, 0);
          acc3[mi][ni] = __builtin_amdgcn_mfma_f32_16x16x32_bf16(a[mi], b3[ni], acc3[mi][ni], 0, 0, 0);
        }
    }
    __syncthreads();
  }

  const int be = base[e];
#pragma unroll
  for (int mi = 0; mi < 4; mi++)
#pragma unroll
    for (int ni = 0; ni < 2; ni++)
#pragma unroll
      for (int r = 0; r < 4; r++) {
        int row = wm + mi * 16 + (lane >> 4) * 4 + r;
        int col = wn + ni * 16 + lr;
        int i = m0 + row;
        if (i < ce) {
          float h1 = acc1[mi][ni][r];
          float h3 = acc3[mi][ni][r];
          float g  = h1 / (1.f + expf(-h1)) * h3 * w_lds[row];
          G[(size_t)(be + i) * FFN_D + n0 + col] = f2bf(g);
        }
      }
}

// ---------------- Down-proj: BM=128, BN=128, BK=64 -> bf16 slot rows Gd ----
__launch_bounds__(256)
__global__ void downproj_fast(const unsigned short* __restrict__ G,
                              const unsigned short* __restrict__ W2b,
                              const int* __restrict__ cnt,
                              const int* __restrict__ base,
                              unsigned short* __restrict__ Gd) {
  const int e  = blockIdx.z;
  const int m0 = blockIdx.y * 128;
  const int n0 = blockIdx.x * 128;
  const int ce = cnt[e];
  if (m0 >= ce) return;
  const int be = base[e];

  __shared__ __align__(16) unsigned short As[2 * 128 * 32];
  __shared__ __align__(16) unsigned short Bs[2 * 128 * 32];

  const int tid  = threadIdx.x;
  const int lane = tid & 63;
  const int wv   = tid >> 6;

  const unsigned short* gA[2];
  const unsigned short* gB[2];
#pragma unroll
  for (int c = 0; c < 2; c++) {
    int r = m0 + wv * 32 + c * 16 + (lane >> 2);
    if (r >= ce) r = ce - 1;
    gA[c] = G + (size_t)(be + r) * FFN_D + (lane & 3) * 8;
    int rb = wv * 32 + c * 16 + (lane >> 2);
    gB[c] = W2b + (size_t)e * H_DIM * FFN_D + (size_t)(n0 + rb) * FFN_D + (lane & 3) * 8;
  }

  const int wm = (wv & 1) * 64;
  const int wn = (wv >> 1) * 64;
  const int qk = (lane >> 4) * 8;
  const int lr = lane & 15;

  f32x4 acc[4][4];
#pragma unroll
  for (int mi = 0; mi < 4; mi++)
#pragma unroll
    for (int ni = 0; ni < 4; ni++) acc[mi][ni] = (f32x4)0.f;

  for (int kt = 0; kt < FFN_D; kt += 64) {
#pragma unroll
    for (int h = 0; h < 2; h++) {
      async16(gA[0] + kt + h * 32, &As[h * 4096 + (wv * 32 + 0)  * 32]);
      async16(gA[1] + kt + h * 32, &As[h * 4096 + (wv * 32 + 16) * 32]);
      async16(gB[0] + kt + h * 32, &Bs[h * 4096 + (wv * 32 + 0)  * 32]);
      async16(gB[1] + kt + h * 32, &Bs[h * 4096 + (wv * 32 + 16) * 32]);
    }
    __syncthreads();

#pragma unroll
    for (int h = 0; h < 2; h++) {
      bf16x8 a[4], b[4];
#pragma unroll
      for (int mi = 0; mi < 4; mi++)
        a[mi] = *(const bf16x8*)&As[h * 4096 + (wm + mi * 16 + lr) * 32 + qk];
#pragma unroll
      for (int ni = 0; ni < 4; ni++)
        b[ni] = *(const bf16x8*)&Bs[h * 4096 + (wn + ni * 16 + lr) * 32 + qk];
#pragma unroll
      for (int mi = 0; mi < 4; mi++)
#pragma unroll
        for (int ni = 0; ni < 4; ni++)
          acc[mi][ni] = __builtin_amdgcn_mfma_f32_16x16x32_bf16(a[mi], b[ni], acc[mi][ni], 0, 0, 0);
    }
    __syncthreads();
  }

#pragma unroll
  for (int mi = 0; mi < 4; mi++)
#pragma unroll
    for (int ni = 0; ni < 4; ni++)
#pragma unroll
      for (int r = 0; r < 4; r++) {
        int row = wm + mi * 16 + (lane >> 4) * 4 + r;
        int col = wn + ni * 16 + lr;
        int i = m0 + row;
        if (i < ce)
          Gd[(size_t)(be + i) * H_DIM + n0 + col] = f2bf(acc[mi][ni][r]);
      }
}

// ---------------- Combine: out[t] = Gd[slot1] + Gd[slot2] ----
__global__ void combine_kernel(const unsigned short* __restrict__ Gd,
                               const int* __restrict__ base,
                               const int* __restrict__ tok2slot,
                               float* __restrict__ out) {
  const int t = blockIdx.x;
  const int v1 = tok2slot[2 * t], v2 = tok2slot[2 * t + 1];
  const int s1 = base[v1 >> 12] + (v1 & 4095);
  const int s2 = base[v2 >> 12] + (v2 & 4095);
  const us4* r1 = (const us4*)(Gd + (size_t)s1 * H_DIM);
  const us4* r2 = (const us4*)(Gd + (size_t)s2 * H_DIM);
  float4* o = (float4*)(out + (size_t)t * H_DIM);
#pragma unroll
  for (int j = 0; j < 2; j++) {
    int i = j * 256 + threadIdx.x;
    us4 a = r1[i], b = r2[i];
    float4 r;
    r.x = bf2f(a.x) + bf2f(b.x);
    r.y = bf2f(a.y) + bf2f(b.y);
    r.z = bf2f(a.z) + bf2f(b.z);
    r.w = bf2f(a.w) + bf2f(b.w);
    o[i] = r;
  }
}

// ---------------- Launch ----------------
extern "C" void kernel_launch(void* const* d_in, const int* in_sizes, int n_in,
                              void* d_out, int out_size, void* d_ws, size_t ws_size,
                              hipStream_t stream) {
  (void)in_sizes; (void)n_in; (void)out_size; (void)ws_size;
  const float* x    = (const float*)d_in[0];
  const float* Wg   = (const float*)d_in[1];
  const float* W1   = (const float*)d_in[2];
  const float* W2   = (const float*)d_in[3];
  const float* W3   = (const float*)d_in[4];
  const float* bias = (const float*)d_in[5];
  float* out = (float*)d_out;

  char* ws = (char*)d_ws;
  const size_t OFF_CNT   = 0;
  const size_t OFF_BASE  = 64;
  const size_t OFF_T2S   = 1024;                       // 32 KB
  const size_t OFF_ROWS  = 65536;                      // 128 KB
  const size_t OFF_WTS   = OFF_ROWS + 131072;          // 128 KB
  const size_t OFF_EPAIR = OFF_WTS + 131072;           // 16 KB
  const size_t OFF_WPAIR = OFF_EPAIR + 16384;          // 32 KB
  const size_t OFF_XB    = 1048576;                    // 16 MB
  const size_t OFF_W1B   = OFF_XB + 16777216;          // 32 MB (Gd aliases after upproj)
  const size_t OFF_W3B   = OFF_W1B + 33554432;         // 32 MB (W2b aliases after upproj)
  const size_t OFF_G     = OFF_W3B + 33554432;         // 16 MB
  // total ~97 MB (same as round-2, proven to fit)

  int*   cnt   = (int*)(ws + OFF_CNT);
  int*   base  = (int*)(ws + OFF_BASE);
  int*   t2s   = (int*)(ws + OFF_T2S);
  int*   rows  = (int*)(ws + OFF_ROWS);
  float* wts   = (float*)(ws + OFF_WTS);
  unsigned* epair = (unsigned*)(ws + OFF_EPAIR);
  float* wpair = (float*)(ws + OFF_WPAIR);
  unsigned short* Xb  = (unsigned short*)(ws + OFF_XB);
  unsigned short* W1b = (unsigned short*)(ws + OFF_W1B);
  unsigned short* W3b = (unsigned short*)(ws + OFF_W3B);
  unsigned short* W2b = (unsigned short*)(ws + OFF_W3B);  // alias: W3b dead after upproj
  unsigned short* Gd  = (unsigned short*)(ws + OFF_W1B);  // alias: W1b dead after upproj
  unsigned short* G   = (unsigned short*)(ws + OFF_G);

  router2_kernel<<<T_TOK / 4, 256, 0, stream>>>(x, Wg, bias, epair, wpair, Xb);
  compact_kernel<<<1, 512, 0, stream>>>(epair, wpair, cnt, base, rows, wts, t2s);

  const size_t N4 = (size_t)NE * FFN_D * H_DIM / 4;      // 4M float4 per weight tensor
  convert2_kernel<<<(unsigned)(2 * N4 / 256), 256, 0, stream>>>(W1, W1b, W3, W3b);

  dim3 g2(FFN_D / 64, T_TOK / 128, NE);
  upproj_fast<<<g2, 256, 0, stream>>>(Xb, W1b, W3b, cnt, base, rows, wts, G);

  convert_kernel<<<(unsigned)(N4 / 256), 256, 0, stream>>>(W2, W2b);

  dim3 g3(H_DIM / 128, T_TOK / 128, NE);
  downproj_fast<<<g3, 256, 0, stream>>>(G, W2b, cnt, base, Gd);

  combine_kernel<<<T_TOK, 256, 0, stream>>>(Gd, base, t2s, out);
}

// Round 4
// 461.450 us; speedup vs baseline: 1.3449x; 1.0096x over previous
//
#include <hip/hip_runtime.h>
#include <hip/hip_bf16.h>

// MoE top-2/8, T=4096, H=2048, FFN=1024.
// 5 dispatches: router (no atomics, +x->bf16) ->
//   convert_all (W1,W3,W2 fp32->bf16; last block does token compaction) ->
//   upproj (BK=32, global_load_lds) -> downproj (BK=32) -> combine.

#define T_TOK 4096
#define H_DIM 2048
#define FFN_D 1024
#define NE    8

typedef __attribute__((ext_vector_type(8))) short          bf16x8;
typedef __attribute__((ext_vector_type(4))) float          f32x4;
typedef __attribute__((ext_vector_type(4))) unsigned short us4;

__device__ __forceinline__ unsigned short f2bf(float f) {
  unsigned u = __builtin_bit_cast(unsigned, f);
  u += 0x7fffu + ((u >> 16) & 1u);
  return (unsigned short)(u >> 16);
}
__device__ __forceinline__ float bf2f(unsigned short u) {
  return __builtin_bit_cast(float, ((unsigned)u) << 16);
}
__device__ __forceinline__ void async16(const void* g, void* l) {
  __builtin_amdgcn_global_load_lds((const __attribute__((address_space(1))) void*)g,
                                   (__attribute__((address_space(3))) void*)l, 16, 0, 0);
}

// ---------------- Router: wave/token, NO atomics. Writes epair/wpair + bf16 x. ----
__global__ void router2_kernel(const float* __restrict__ x,
                               const float* __restrict__ Wg,
                               const float* __restrict__ bias,
                               unsigned* __restrict__ epair,
                               float* __restrict__ wpair,
                               unsigned short* __restrict__ Xb) {
  const int wv   = threadIdx.x >> 6;
  const int lane = threadIdx.x & 63;
  const int t    = blockIdx.x * 4 + wv;

  const float4* xr = (const float4*)(x + (size_t)t * H_DIM);
  us4*          xb = (us4*)(Xb + (size_t)t * H_DIM);

  float acc[NE];
#pragma unroll
  for (int e = 0; e < NE; e++) acc[e] = 0.f;

#pragma unroll
  for (int j = 0; j < 8; j++) {
    int i4 = j * 64 + lane;
    float4 v = xr[i4];
    us4 d; d.x = f2bf(v.x); d.y = f2bf(v.y); d.z = f2bf(v.z); d.w = f2bf(v.w);
    xb[i4] = d;
#pragma unroll
    for (int e = 0; e < NE; e++) {
      float4 w = ((const float4*)(Wg + e * H_DIM))[i4];
      acc[e] += v.x * w.x + v.y * w.y + v.z * w.z + v.w * w.w;
    }
  }
#pragma unroll
  for (int e = 0; e < NE; e++) {
#pragma unroll
    for (int m = 32; m >= 1; m >>= 1) acc[e] += __shfl_xor(acc[e], m, 64);
  }

  if (lane == 0) {
    float sig[NE], sc[NE];
#pragma unroll
    for (int e = 0; e < NE; e++) {
      sig[e] = 1.f / (1.f + expf(-acc[e]));
      sc[e]  = sig[e] + bias[e];
    }
    int i1 = 0; float v1 = sc[0];
#pragma unroll
    for (int e = 1; e < NE; e++) if (sc[e] > v1) { v1 = sc[e]; i1 = e; }
    int i2 = -1; float v2 = -1e30f;
#pragma unroll
    for (int e = 0; e < NE; e++) if (e != i1 && sc[e] > v2) { v2 = sc[e]; i2 = e; }
    float w1 = sig[i1], w2 = sig[i2];
    float s = w1 + w2;
    epair[t] = (unsigned)i1 | ((unsigned)i2 << 8);
    wpair[2 * t]     = w1 / s;
    wpair[2 * t + 1] = w2 / s;
  }
}

// ---------------- convert_all: W1,W3,W2 fp32->bf16; LAST block compacts tokens. ----
// Grid: NB_CONV + 1 blocks of 512 threads. Blocks [0,NB_CONV) each convert 512 float4.
// Block NB_CONV: 8 waves, wave e builds expert e's slot list via ballot prefix.
#define N4_PER_W ((size_t)NE * FFN_D * H_DIM / 4)   // 4,194,304 float4 per weight tensor
#define NB_CONV  ((unsigned)(3 * N4_PER_W / 512))   // 24576

__global__ void convert_all_kernel(const float* __restrict__ W1, unsigned short* __restrict__ W1b,
                                   const float* __restrict__ W3, unsigned short* __restrict__ W3b,
                                   const float* __restrict__ W2, unsigned short* __restrict__ W2b,
                                   const unsigned* __restrict__ epair,
                                   const float* __restrict__ wpair,
                                   int* __restrict__ cnt, int* __restrict__ base,
                                   int* __restrict__ rows, float* __restrict__ wts,
                                   int* __restrict__ t2s) {
  if (blockIdx.x < NB_CONV) {
    size_t i = (size_t)blockIdx.x * 512 + threadIdx.x;
    const float* s; unsigned short* d;
    if (i < N4_PER_W)            { s = W1; d = W1b; }
    else if (i < 2 * N4_PER_W)   { s = W3; d = W3b; i -= N4_PER_W; }
    else                         { s = W2; d = W2b; i -= 2 * N4_PER_W; }
    float4 v = ((const float4*)s)[i];
    us4 o; o.x = f2bf(v.x); o.y = f2bf(v.y); o.z = f2bf(v.z); o.w = f2bf(v.w);
    ((us4*)d)[i] = o;
    return;
  }
  // compaction block
  const int e    = threadIdx.x >> 6;
  const int lane = threadIdx.x & 63;
  const unsigned long long ltmask = ((unsigned long long)1 << lane) - 1;
  __shared__ int cnts[NE];

  int count = 0;
  for (int c = 0; c < T_TOK; c += 64) {
    int t = c + lane;
    unsigned ep = epair[t];
    bool m1 = ((ep & 255u) == (unsigned)e);
    bool m2 = (((ep >> 8) & 255u) == (unsigned)e);
    unsigned long long b1 = __ballot(m1);
    if (m1) {
      int p = count + __popcll(b1 & ltmask);
      rows[e * T_TOK + p] = t;
      wts [e * T_TOK + p] = wpair[2 * t];
      t2s[2 * t] = (e << 12) | p;
    }
    count += __popcll(b1);
    unsigned long long b2 = __ballot(m2);
    if (m2) {
      int p = count + __popcll(b2 & ltmask);
      rows[e * T_TOK + p] = t;
      wts [e * T_TOK + p] = wpair[2 * t + 1];
      t2s[2 * t + 1] = (e << 12) | p;
    }
    count += __popcll(b2);
  }
  if (lane == 0) { cnts[e] = count; cnt[e] = count; }
  __syncthreads();
  if (threadIdx.x == 0) {
    int s = 0;
    for (int i = 0; i < NE; i++) { base[i] = s; s += cnts[i]; }
    base[NE] = s;
  }
}

// ---------------- Up-proj: BM=128 x BN=64 (x2 mats), BK=32 (R2-proven) ----
__launch_bounds__(256)
__global__ void upproj_fast(const unsigned short* __restrict__ Xb,
                            const unsigned short* __restrict__ W1b,
                            const unsigned short* __restrict__ W3b,
                            const int* __restrict__ cnt,
                            const int* __restrict__ base,
                            const int* __restrict__ rows,
                            const float* __restrict__ wts,
                            unsigned short* __restrict__ G) {
  const int e  = blockIdx.z;
  const int m0 = blockIdx.y * 128;
  const int n0 = blockIdx.x * 64;
  const int ce = cnt[e];
  if (m0 >= ce) return;

  __shared__ __align__(16) unsigned short As [128 * 32];
  __shared__ __align__(16) unsigned short B1s[64 * 32];
  __shared__ __align__(16) unsigned short B3s[64 * 32];
  __shared__ int   t_ids[128];
  __shared__ float w_lds[128];

  const int tid = threadIdx.x;
  if (tid < 128) {
    int i = m0 + tid;
    if (i < ce) { t_ids[tid] = rows[e * T_TOK + i]; w_lds[tid] = wts[e * T_TOK + i]; }
    else        { t_ids[tid] = 0;                   w_lds[tid] = 0.f; }
  }
  __syncthreads();

  const int lane = tid & 63;
  const int wv   = tid >> 6;

  const unsigned short* gA[2];
#pragma unroll
  for (int c = 0; c < 2; c++) {
    int r = wv * 32 + c * 16 + (lane >> 2);
    gA[c] = Xb + (size_t)t_ids[r] * H_DIM + (lane & 3) * 8;
  }
  const size_t wrow = (size_t)(n0 + wv * 16 + (lane >> 2));
  const unsigned short* gB1 = W1b + (size_t)e * FFN_D * H_DIM + wrow * H_DIM + (lane & 3) * 8;
  const unsigned short* gB3 = W3b + (size_t)e * FFN_D * H_DIM + wrow * H_DIM + (lane & 3) * 8;
  unsigned short* lA0 = &As [(wv * 32 + 0)  * 32];
  unsigned short* lA1 = &As [(wv * 32 + 16) * 32];
  unsigned short* lB1 = &B1s[(wv * 16) * 32];
  unsigned short* lB3 = &B3s[(wv * 16) * 32];

  const int wm = (wv & 1) * 64;
  const int wn = (wv >> 1) * 32;
  const int qk = (lane >> 4) * 8;
  const int lr = lane & 15;

  f32x4 acc1[4][2], acc3[4][2];
#pragma unroll
  for (int mi = 0; mi < 4; mi++)
#pragma unroll
    for (int ni = 0; ni < 2; ni++) { acc1[mi][ni] = (f32x4)0.f; acc3[mi][ni] = (f32x4)0.f; }

  for (int kt = 0; kt < H_DIM; kt += 32) {
    async16(gA[0] + kt, lA0);
    async16(gA[1] + kt, lA1);
    async16(gB1 + kt,   lB1);
    async16(gB3 + kt,   lB3);
    __syncthreads();

    bf16x8 a[4], b1[2], b3[2];
#pragma unroll
    for (int mi = 0; mi < 4; mi++)
      a[mi] = *(const bf16x8*)&As[(wm + mi * 16 + lr) * 32 + qk];
#pragma unroll
    for (int ni = 0; ni < 2; ni++) {
      b1[ni] = *(const bf16x8*)&B1s[(wn + ni * 16 + lr) * 32 + qk];
      b3[ni] = *(const bf16x8*)&B3s[(wn + ni * 16 + lr) * 32 + qk];
    }
#pragma unroll
    for (int mi = 0; mi < 4; mi++)
#pragma unroll
      for (int ni = 0; ni < 2; ni++) {
        acc1[mi][ni] = __builtin_amdgcn_mfma_f32_16x16x32_bf16(a[mi], b1[ni], acc1[mi][ni], 0, 0, 0);
        acc3[mi][ni] = __builtin_amdgcn_mfma_f32_16x16x32_bf16(a[mi], b3[ni], acc3[mi][ni], 0, 0, 0);
      }
    __syncthreads();
  }

  const int be = base[e];
#pragma unroll
  for (int mi = 0; mi < 4; mi++)
#pragma unroll
    for (int ni = 0; ni < 2; ni++)
#pragma unroll
      for (int r = 0; r < 4; r++) {
        int row = wm + mi * 16 + (lane >> 4) * 4 + r;
        int col = wn + ni * 16 + lr;
        int i = m0 + row;
        if (i < ce) {
          float h1 = acc1[mi][ni][r];
          float h3 = acc3[mi][ni][r];
          float g  = h1 / (1.f + expf(-h1)) * h3 * w_lds[row];
          G[(size_t)(be + i) * FFN_D + n0 + col] = f2bf(g);
        }
      }
}

// ---------------- Down-proj: BM=128 x BN=128, BK=32 (R2-proven) -> bf16 Gd ----
__launch_bounds__(256)
__global__ void downproj_fast(const unsigned short* __restrict__ G,
                              const unsigned short* __restrict__ W2b,
                              const int* __restrict__ cnt,
                              const int* __restrict__ base,
                              unsigned short* __restrict__ Gd) {
  const int e  = blockIdx.z;
  const int m0 = blockIdx.y * 128;
  const int n0 = blockIdx.x * 128;
  const int ce = cnt[e];
  if (m0 >= ce) return;
  const int be = base[e];

  __shared__ __align__(16) unsigned short As[128 * 32];
  __shared__ __align__(16) unsigned short Bs[128 * 32];

  const int tid  = threadIdx.x;
  const int lane = tid & 63;
  const int wv   = tid >> 6;

  const unsigned short* gA[2];
  const unsigned short* gB[2];
#pragma unroll
  for (int c = 0; c < 2; c++) {
    int r = m0 + wv * 32 + c * 16 + (lane >> 2);
    if (r >= ce) r = ce - 1;
    gA[c] = G + (size_t)(be + r) * FFN_D + (lane & 3) * 8;
    int rb = wv * 32 + c * 16 + (lane >> 2);
    gB[c] = W2b + (size_t)e * H_DIM * FFN_D + (size_t)(n0 + rb) * FFN_D + (lane & 3) * 8;
  }
  unsigned short* lA[2] = { &As[(wv * 32 + 0) * 32], &As[(wv * 32 + 16) * 32] };
  unsigned short* lB[2] = { &Bs[(wv * 32 + 0) * 32], &Bs[(wv * 32 + 16) * 32] };

  const int wm = (wv & 1) * 64;
  const int wn = (wv >> 1) * 64;
  const int qk = (lane >> 4) * 8;
  const int lr = lane & 15;

  f32x4 acc[4][4];
#pragma unroll
  for (int mi = 0; mi < 4; mi++)
#pragma unroll
    for (int ni = 0; ni < 4; ni++) acc[mi][ni] = (f32x4)0.f;

  for (int kt = 0; kt < FFN_D; kt += 32) {
    async16(gA[0] + kt, lA[0]);
    async16(gA[1] + kt, lA[1]);
    async16(gB[0] + kt, lB[0]);
    async16(gB[1] + kt, lB[1]);
    __syncthreads();

    bf16x8 a[4], b[4];
#pragma unroll
    for (int mi = 0; mi < 4; mi++)
      a[mi] = *(const bf16x8*)&As[(wm + mi * 16 + lr) * 32 + qk];
#pragma unroll
    for (int ni = 0; ni < 4; ni++)
      b[ni] = *(const bf16x8*)&Bs[(wn + ni * 16 + lr) * 32 + qk];
#pragma unroll
    for (int mi = 0; mi < 4; mi++)
#pragma unroll
      for (int ni = 0; ni < 4; ni++)
        acc[mi][ni] = __builtin_amdgcn_mfma_f32_16x16x32_bf16(a[mi], b[ni], acc[mi][ni], 0, 0, 0);
    __syncthreads();
  }

#pragma unroll
  for (int mi = 0; mi < 4; mi++)
#pragma unroll
    for (int ni = 0; ni < 4; ni++)
#pragma unroll
      for (int r = 0; r < 4; r++) {
        int row = wm + mi * 16 + (lane >> 4) * 4 + r;
        int col = wn + ni * 16 + lr;
        int i = m0 + row;
        if (i < ce)
          Gd[(size_t)(be + i) * H_DIM + n0 + col] = f2bf(acc[mi][ni][r]);
      }
}

// ---------------- Combine: out[t] = Gd[slot1] + Gd[slot2] ----
__global__ void combine_kernel(const unsigned short* __restrict__ Gd,
                               const int* __restrict__ base,
                               const int* __restrict__ tok2slot,
                               float* __restrict__ out) {
  const int t = blockIdx.x;
  const int v1 = tok2slot[2 * t], v2 = tok2slot[2 * t + 1];
  const int s1 = base[v1 >> 12] + (v1 & 4095);
  const int s2 = base[v2 >> 12] + (v2 & 4095);
  const us4* r1 = (const us4*)(Gd + (size_t)s1 * H_DIM);
  const us4* r2 = (const us4*)(Gd + (size_t)s2 * H_DIM);
  float4* o = (float4*)(out + (size_t)t * H_DIM);
#pragma unroll
  for (int j = 0; j < 2; j++) {
    int i = j * 256 + threadIdx.x;
    us4 a = r1[i], b = r2[i];
    float4 r;
    r.x = bf2f(a.x) + bf2f(b.x);
    r.y = bf2f(a.y) + bf2f(b.y);
    r.z = bf2f(a.z) + bf2f(b.z);
    r.w = bf2f(a.w) + bf2f(b.w);
    o[i] = r;
  }
}

// ---------------- Launch ----------------
extern "C" void kernel_launch(void* const* d_in, const int* in_sizes, int n_in,
                              void* d_out, int out_size, void* d_ws, size_t ws_size,
                              hipStream_t stream) {
  (void)in_sizes; (void)n_in; (void)out_size; (void)ws_size;
  const float* x    = (const float*)d_in[0];
  const float* Wg   = (const float*)d_in[1];
  const float* W1   = (const float*)d_in[2];
  const float* W2   = (const float*)d_in[3];
  const float* W3   = (const float*)d_in[4];
  const float* bias = (const float*)d_in[5];
  float* out = (float*)d_out;

  char* ws = (char*)d_ws;
  const size_t OFF_CNT   = 0;
  const size_t OFF_BASE  = 64;
  const size_t OFF_T2S   = 1024;                       // 32 KB
  const size_t OFF_ROWS  = 65536;                      // 128 KB
  const size_t OFF_WTS   = OFF_ROWS + 131072;          // 128 KB
  const size_t OFF_EPAIR = OFF_WTS + 131072;           // 16 KB
  const size_t OFF_WPAIR = OFF_EPAIR + 16384;          // 32 KB
  const size_t OFF_XB    = 1048576;                    // 16 MB
  const size_t OFF_W1B   = OFF_XB + 16777216;          // 32 MB (Gd aliases after upproj)
  const size_t OFF_W3B   = OFF_W1B + 33554432;         // 32 MB
  const size_t OFF_G     = OFF_W3B + 33554432;         // 16 MB
  const size_t OFF_W2B   = OFF_G + 16777216;           // 32 MB
  // total ~129 MB

  int*   cnt   = (int*)(ws + OFF_CNT);
  int*   base  = (int*)(ws + OFF_BASE);
  int*   t2s   = (int*)(ws + OFF_T2S);
  int*   rows  = (int*)(ws + OFF_ROWS);
  float* wts   = (float*)(ws + OFF_WTS);
  unsigned* epair = (unsigned*)(ws + OFF_EPAIR);
  float* wpair = (float*)(ws + OFF_WPAIR);
  unsigned short* Xb  = (unsigned short*)(ws + OFF_XB);
  unsigned short* W1b = (unsigned short*)(ws + OFF_W1B);
  unsigned short* W3b = (unsigned short*)(ws + OFF_W3B);
  unsigned short* W2b = (unsigned short*)(ws + OFF_W2B);
  unsigned short* Gd  = (unsigned short*)(ws + OFF_W1B);  // alias: W1b dead after upproj
  unsigned short* G   = (unsigned short*)(ws + OFF_G);

  router2_kernel<<<T_TOK / 4, 256, 0, stream>>>(x, Wg, bias, epair, wpair, Xb);

  convert_all_kernel<<<NB_CONV + 1, 512, 0, stream>>>(W1, W1b, W3, W3b, W2, W2b,
                                                      epair, wpair, cnt, base, rows, wts, t2s);

  dim3 g2(FFN_D / 64, T_TOK / 128, NE);
  upproj_fast<<<g2, 256, 0, stream>>>(Xb, W1b, W3b, cnt, base, rows, wts, G);

  dim3 g3(H_DIM / 128, T_TOK / 128, NE);
  downproj_fast<<<g3, 256, 0, stream>>>(G, W2b, cnt, base, Gd);

  combine_kernel<<<T_TOK, 256, 0, stream>>>(Gd, base, t2s, out);
}

// Round 5
// 442.857 us; speedup vs baseline: 1.4014x; 1.0420x over previous
//
#include <hip/hip_runtime.h>
#include <hip/hip_bf16.h>

// MoE top-2/8, T=4096, H=2048, FFN=1024.
// 5 dispatches:
//   router_conv (router + W1/W3 fp32->bf16 convert, overlapped in one grid)
//   compact (1 block, ballot prefix)
//   upproj (BK=32, global_load_lds; z==8 slice converts W2 concurrently)
//   downproj (BK=32) -> combine.

#define T_TOK 4096
#define H_DIM 2048
#define FFN_D 1024
#define NE    8

typedef __attribute__((ext_vector_type(8))) short          bf16x8;
typedef __attribute__((ext_vector_type(4))) float          f32x4;
typedef __attribute__((ext_vector_type(4))) unsigned short us4;

#define N4_PER_W ((size_t)NE * FFN_D * H_DIM / 4)   // 4,194,304 float4 per weight tensor
#define RB_ROUTER 1024u                             // router blocks (4 tokens each)
#define CB_CONV   8192u                             // convert blocks for W1+W3 (1024 float4 each)

__device__ __forceinline__ unsigned short f2bf(float f) {
  unsigned u = __builtin_bit_cast(unsigned, f);
  u += 0x7fffu + ((u >> 16) & 1u);
  return (unsigned short)(u >> 16);
}
__device__ __forceinline__ float bf2f(unsigned short u) {
  return __builtin_bit_cast(float, ((unsigned)u) << 16);
}
__device__ __forceinline__ void async16(const void* g, void* l) {
  __builtin_amdgcn_global_load_lds((const __attribute__((address_space(1))) void*)g,
                                   (__attribute__((address_space(3))) void*)l, 16, 0, 0);
}

// ---------------- K1: router (blocks 0..1023) + W1/W3 convert (blocks 1024..9215) ----
__global__ void router_conv_kernel(const float* __restrict__ x,
                                   const float* __restrict__ Wg,
                                   const float* __restrict__ bias,
                                   unsigned* __restrict__ epair,
                                   float* __restrict__ wpair,
                                   unsigned short* __restrict__ Xb,
                                   const float* __restrict__ W1, unsigned short* __restrict__ W1b,
                                   const float* __restrict__ W3, unsigned short* __restrict__ W3b) {
  if (blockIdx.x >= RB_ROUTER) {
    // -------- convert path: 1024 float4 per block, coalesced --------
    size_t b0 = (size_t)(blockIdx.x - RB_ROUTER) * 1024;
#pragma unroll
    for (int k = 0; k < 4; k++) {
      size_t i = b0 + k * 256 + threadIdx.x;
      const float* s; unsigned short* d;
      if (i < N4_PER_W) { s = W1; d = W1b; } else { s = W3; d = W3b; i -= N4_PER_W; }
      float4 v = ((const float4*)s)[i];
      us4 o; o.x = f2bf(v.x); o.y = f2bf(v.y); o.z = f2bf(v.z); o.w = f2bf(v.w);
      ((us4*)d)[i] = o;
    }
    return;
  }
  // -------- router path: one wave per token --------
  const int wv   = threadIdx.x >> 6;
  const int lane = threadIdx.x & 63;
  const int t    = blockIdx.x * 4 + wv;

  const float4* xr = (const float4*)(x + (size_t)t * H_DIM);
  us4*          xb = (us4*)(Xb + (size_t)t * H_DIM);

  float acc[NE];
#pragma unroll
  for (int e = 0; e < NE; e++) acc[e] = 0.f;

#pragma unroll
  for (int j = 0; j < 8; j++) {
    int i4 = j * 64 + lane;
    float4 v = xr[i4];
    us4 d; d.x = f2bf(v.x); d.y = f2bf(v.y); d.z = f2bf(v.z); d.w = f2bf(v.w);
    xb[i4] = d;
#pragma unroll
    for (int e = 0; e < NE; e++) {
      float4 w = ((const float4*)(Wg + e * H_DIM))[i4];
      acc[e] += v.x * w.x + v.y * w.y + v.z * w.z + v.w * w.w;
    }
  }
#pragma unroll
  for (int e = 0; e < NE; e++) {
#pragma unroll
    for (int m = 32; m >= 1; m >>= 1) acc[e] += __shfl_xor(acc[e], m, 64);
  }

  if (lane == 0) {
    float sig[NE], sc[NE];
#pragma unroll
    for (int e = 0; e < NE; e++) {
      sig[e] = 1.f / (1.f + expf(-acc[e]));
      sc[e]  = sig[e] + bias[e];
    }
    int i1 = 0; float v1 = sc[0];
#pragma unroll
    for (int e = 1; e < NE; e++) if (sc[e] > v1) { v1 = sc[e]; i1 = e; }
    int i2 = -1; float v2 = -1e30f;
#pragma unroll
    for (int e = 0; e < NE; e++) if (e != i1 && sc[e] > v2) { v2 = sc[e]; i2 = e; }
    float w1 = sig[i1], w2 = sig[i2];
    float s = w1 + w2;
    epair[t] = (unsigned)i1 | ((unsigned)i2 << 8);
    wpair[2 * t]     = w1 / s;
    wpair[2 * t + 1] = w2 / s;
  }
}

// ---------------- K2: compaction, ONE block, 8 waves (wave e scans all tokens) ----
__global__ void compact_kernel(const unsigned* __restrict__ epair,
                               const float* __restrict__ wpair,
                               int* __restrict__ cnt,
                               int* __restrict__ base,
                               int* __restrict__ rows,
                               float* __restrict__ wts,
                               int* __restrict__ t2s) {
  const int e    = threadIdx.x >> 6;
  const int lane = threadIdx.x & 63;
  const unsigned long long ltmask = ((unsigned long long)1 << lane) - 1;
  __shared__ int cnts[NE];

  int count = 0;
  for (int c = 0; c < T_TOK; c += 64) {
    int t = c + lane;
    unsigned ep = epair[t];
    bool m1 = ((ep & 255u) == (unsigned)e);
    bool m2 = (((ep >> 8) & 255u) == (unsigned)e);
    unsigned long long b1 = __ballot(m1);
    if (m1) {
      int p = count + __popcll(b1 & ltmask);
      rows[e * T_TOK + p] = t;
      wts [e * T_TOK + p] = wpair[2 * t];
      t2s[2 * t] = (e << 12) | p;
    }
    count += __popcll(b1);
    unsigned long long b2 = __ballot(m2);
    if (m2) {
      int p = count + __popcll(b2 & ltmask);
      rows[e * T_TOK + p] = t;
      wts [e * T_TOK + p] = wpair[2 * t + 1];
      t2s[2 * t + 1] = (e << 12) | p;
    }
    count += __popcll(b2);
  }
  if (lane == 0) { cnts[e] = count; cnt[e] = count; }
  __syncthreads();
  if (threadIdx.x == 0) {
    int s = 0;
    for (int i = 0; i < NE; i++) { base[i] = s; s += cnts[i]; }
    base[NE] = s;
  }
}

// ---------------- K3: up-proj BM=128 x BN=64 (x2 mats), BK=32.
// blockIdx.z == NE: W2 fp32->bf16 convert slice (overlaps with GEMM blocks). ----
__launch_bounds__(256)
__global__ void upproj_fast(const unsigned short* __restrict__ Xb,
                            const unsigned short* __restrict__ W1b,
                            const unsigned short* __restrict__ W3b,
                            const int* __restrict__ cnt,
                            const int* __restrict__ base,
                            const int* __restrict__ rows,
                            const float* __restrict__ wts,
                            unsigned short* __restrict__ G,
                            const float* __restrict__ W2, unsigned short* __restrict__ W2b) {
  if (blockIdx.z == NE) {
    // -------- W2 convert slice: 512 blocks x 8192 float4 --------
    size_t flat = (size_t)blockIdx.y * 16 + blockIdx.x;   // 0..511
    size_t b0 = flat * 8192;
#pragma unroll
    for (int k = 0; k < 32; k++) {
      size_t i = b0 + (size_t)k * 256 + threadIdx.x;
      float4 v = ((const float4*)W2)[i];
      us4 o; o.x = f2bf(v.x); o.y = f2bf(v.y); o.z = f2bf(v.z); o.w = f2bf(v.w);
      ((us4*)W2b)[i] = o;
    }
    return;
  }
  const int e  = blockIdx.z;
  const int m0 = blockIdx.y * 128;
  const int n0 = blockIdx.x * 64;
  const int ce = cnt[e];
  if (m0 >= ce) return;

  __shared__ __align__(16) unsigned short As [128 * 32];
  __shared__ __align__(16) unsigned short B1s[64 * 32];
  __shared__ __align__(16) unsigned short B3s[64 * 32];
  __shared__ int   t_ids[128];
  __shared__ float w_lds[128];

  const int tid = threadIdx.x;
  if (tid < 128) {
    int i = m0 + tid;
    if (i < ce) { t_ids[tid] = rows[e * T_TOK + i]; w_lds[tid] = wts[e * T_TOK + i]; }
    else        { t_ids[tid] = 0;                   w_lds[tid] = 0.f; }
  }
  __syncthreads();

  const int lane = tid & 63;
  const int wv   = tid >> 6;

  const unsigned short* gA[2];
#pragma unroll
  for (int c = 0; c < 2; c++) {
    int r = wv * 32 + c * 16 + (lane >> 2);
    gA[c] = Xb + (size_t)t_ids[r] * H_DIM + (lane & 3) * 8;
  }
  const size_t wrow = (size_t)(n0 + wv * 16 + (lane >> 2));
  const unsigned short* gB1 = W1b + (size_t)e * FFN_D * H_DIM + wrow * H_DIM + (lane & 3) * 8;
  const unsigned short* gB3 = W3b + (size_t)e * FFN_D * H_DIM + wrow * H_DIM + (lane & 3) * 8;
  unsigned short* lA0 = &As [(wv * 32 + 0)  * 32];
  unsigned short* lA1 = &As [(wv * 32 + 16) * 32];
  unsigned short* lB1 = &B1s[(wv * 16) * 32];
  unsigned short* lB3 = &B3s[(wv * 16) * 32];

  const int wm = (wv & 1) * 64;
  const int wn = (wv >> 1) * 32;
  const int qk = (lane >> 4) * 8;
  const int lr = lane & 15;

  f32x4 acc1[4][2], acc3[4][2];
#pragma unroll
  for (int mi = 0; mi < 4; mi++)
#pragma unroll
    for (int ni = 0; ni < 2; ni++) { acc1[mi][ni] = (f32x4)0.f; acc3[mi][ni] = (f32x4)0.f; }

  for (int kt = 0; kt < H_DIM; kt += 32) {
    async16(gA[0] + kt, lA0);
    async16(gA[1] + kt, lA1);
    async16(gB1 + kt,   lB1);
    async16(gB3 + kt,   lB3);
    __syncthreads();

    bf16x8 a[4], b1[2], b3[2];
#pragma unroll
    for (int mi = 0; mi < 4; mi++)
      a[mi] = *(const bf16x8*)&As[(wm + mi * 16 + lr) * 32 + qk];
#pragma unroll
    for (int ni = 0; ni < 2; ni++) {
      b1[ni] = *(const bf16x8*)&B1s[(wn + ni * 16 + lr) * 32 + qk];
      b3[ni] = *(const bf16x8*)&B3s[(wn + ni * 16 + lr) * 32 + qk];
    }
#pragma unroll
    for (int mi = 0; mi < 4; mi++)
#pragma unroll
      for (int ni = 0; ni < 2; ni++) {
        acc1[mi][ni] = __builtin_amdgcn_mfma_f32_16x16x32_bf16(a[mi], b1[ni], acc1[mi][ni], 0, 0, 0);
        acc3[mi][ni] = __builtin_amdgcn_mfma_f32_16x16x32_bf16(a[mi], b3[ni], acc3[mi][ni], 0, 0, 0);
      }
    __syncthreads();
  }

  const int be = base[e];
#pragma unroll
  for (int mi = 0; mi < 4; mi++)
#pragma unroll
    for (int ni = 0; ni < 2; ni++)
#pragma unroll
      for (int r = 0; r < 4; r++) {
        int row = wm + mi * 16 + (lane >> 4) * 4 + r;
        int col = wn + ni * 16 + lr;
        int i = m0 + row;
        if (i < ce) {
          float h1 = acc1[mi][ni][r];
          float h3 = acc3[mi][ni][r];
          float g  = h1 / (1.f + expf(-h1)) * h3 * w_lds[row];
          G[(size_t)(be + i) * FFN_D + n0 + col] = f2bf(g);
        }
      }
}

// ---------------- K4: down-proj BM=128 x BN=128, BK=32 -> bf16 Gd ----
__launch_bounds__(256)
__global__ void downproj_fast(const unsigned short* __restrict__ G,
                              const unsigned short* __restrict__ W2b,
                              const int* __restrict__ cnt,
                              const int* __restrict__ base,
                              unsigned short* __restrict__ Gd) {
  const int e  = blockIdx.z;
  const int m0 = blockIdx.y * 128;
  const int n0 = blockIdx.x * 128;
  const int ce = cnt[e];
  if (m0 >= ce) return;
  const int be = base[e];

  __shared__ __align__(16) unsigned short As[128 * 32];
  __shared__ __align__(16) unsigned short Bs[128 * 32];

  const int tid  = threadIdx.x;
  const int lane = tid & 63;
  const int wv   = tid >> 6;

  const unsigned short* gA[2];
  const unsigned short* gB[2];
#pragma unroll
  for (int c = 0; c < 2; c++) {
    int r = m0 + wv * 32 + c * 16 + (lane >> 2);
    if (r >= ce) r = ce - 1;
    gA[c] = G + (size_t)(be + r) * FFN_D + (lane & 3) * 8;
    int rb = wv * 32 + c * 16 + (lane >> 2);
    gB[c] = W2b + (size_t)e * H_DIM * FFN_D + (size_t)(n0 + rb) * FFN_D + (lane & 3) * 8;
  }
  unsigned short* lA[2] = { &As[(wv * 32 + 0) * 32], &As[(wv * 32 + 16) * 32] };
  unsigned short* lB[2] = { &Bs[(wv * 32 + 0) * 32], &Bs[(wv * 32 + 16) * 32] };

  const int wm = (wv & 1) * 64;
  const int wn = (wv >> 1) * 64;
  const int qk = (lane >> 4) * 8;
  const int lr = lane & 15;

  f32x4 acc[4][4];
#pragma unroll
  for (int mi = 0; mi < 4; mi++)
#pragma unroll
    for (int ni = 0; ni < 4; ni++) acc[mi][ni] = (f32x4)0.f;

  for (int kt = 0; kt < FFN_D; kt += 32) {
    async16(gA[0] + kt, lA[0]);
    async16(gA[1] + kt, lA[1]);
    async16(gB[0] + kt, lB[0]);
    async16(gB[1] + kt, lB[1]);
    __syncthreads();

    bf16x8 a[4], b[4];
#pragma unroll
    for (int mi = 0; mi < 4; mi++)
      a[mi] = *(const bf16x8*)&As[(wm + mi * 16 + lr) * 32 + qk];
#pragma unroll
    for (int ni = 0; ni < 4; ni++)
      b[ni] = *(const bf16x8*)&Bs[(wn + ni * 16 + lr) * 32 + qk];
#pragma unroll
    for (int mi = 0; mi < 4; mi++)
#pragma unroll
      for (int ni = 0; ni < 4; ni++)
        acc[mi][ni] = __builtin_amdgcn_mfma_f32_16x16x32_bf16(a[mi], b[ni], acc[mi][ni], 0, 0, 0);
    __syncthreads();
  }

#pragma unroll
  for (int mi = 0; mi < 4; mi++)
#pragma unroll
    for (int ni = 0; ni < 4; ni++)
#pragma unroll
      for (int r = 0; r < 4; r++) {
        int row = wm + mi * 16 + (lane >> 4) * 4 + r;
        int col = wn + ni * 16 + lr;
        int i = m0 + row;
        if (i < ce)
          Gd[(size_t)(be + i) * H_DIM + n0 + col] = f2bf(acc[mi][ni][r]);
      }
}

// ---------------- K5: combine out[t] = Gd[slot1] + Gd[slot2] ----
__global__ void combine_kernel(const unsigned short* __restrict__ Gd,
                               const int* __restrict__ base,
                               const int* __restrict__ tok2slot,
                               float* __restrict__ out) {
  const int t = blockIdx.x;
  const int v1 = tok2slot[2 * t], v2 = tok2slot[2 * t + 1];
  const int s1 = base[v1 >> 12] + (v1 & 4095);
  const int s2 = base[v2 >> 12] + (v2 & 4095);
  const us4* r1 = (const us4*)(Gd + (size_t)s1 * H_DIM);
  const us4* r2 = (const us4*)(Gd + (size_t)s2 * H_DIM);
  float4* o = (float4*)(out + (size_t)t * H_DIM);
#pragma unroll
  for (int j = 0; j < 2; j++) {
    int i = j * 256 + threadIdx.x;
    us4 a = r1[i], b = r2[i];
    float4 r;
    r.x = bf2f(a.x) + bf2f(b.x);
    r.y = bf2f(a.y) + bf2f(b.y);
    r.z = bf2f(a.z) + bf2f(b.z);
    r.w = bf2f(a.w) + bf2f(b.w);
    o[i] = r;
  }
}

// ---------------- Launch ----------------
extern "C" void kernel_launch(void* const* d_in, const int* in_sizes, int n_in,
                              void* d_out, int out_size, void* d_ws, size_t ws_size,
                              hipStream_t stream) {
  (void)in_sizes; (void)n_in; (void)out_size; (void)ws_size;
  const float* x    = (const float*)d_in[0];
  const float* Wg   = (const float*)d_in[1];
  const float* W1   = (const float*)d_in[2];
  const float* W2   = (const float*)d_in[3];
  const float* W3   = (const float*)d_in[4];
  const float* bias = (const float*)d_in[5];
  float* out = (float*)d_out;

  char* ws = (char*)d_ws;
  const size_t OFF_CNT   = 0;
  const size_t OFF_BASE  = 64;
  const size_t OFF_T2S   = 1024;                       // 32 KB
  const size_t OFF_ROWS  = 65536;                      // 128 KB
  const size_t OFF_WTS   = OFF_ROWS + 131072;          // 128 KB
  const size_t OFF_EPAIR = OFF_WTS + 131072;           // 16 KB
  const size_t OFF_WPAIR = OFF_EPAIR + 16384;          // 32 KB
  const size_t OFF_XB    = 1048576;                    // 16 MB
  const size_t OFF_W1B   = OFF_XB + 16777216;          // 32 MB (Gd aliases after upproj)
  const size_t OFF_W3B   = OFF_W1B + 33554432;         // 32 MB
  const size_t OFF_G     = OFF_W3B + 33554432;         // 16 MB
  const size_t OFF_W2B   = OFF_G + 16777216;           // 32 MB
  // total ~129 MB (fits, proven R4)

  int*   cnt   = (int*)(ws + OFF_CNT);
  int*   base  = (int*)(ws + OFF_BASE);
  int*   t2s   = (int*)(ws + OFF_T2S);
  int*   rows  = (int*)(ws + OFF_ROWS);
  float* wts   = (float*)(ws + OFF_WTS);
  unsigned* epair = (unsigned*)(ws + OFF_EPAIR);
  float* wpair = (float*)(ws + OFF_WPAIR);
  unsigned short* Xb  = (unsigned short*)(ws + OFF_XB);
  unsigned short* W1b = (unsigned short*)(ws + OFF_W1B);
  unsigned short* W3b = (unsigned short*)(ws + OFF_W3B);
  unsigned short* W2b = (unsigned short*)(ws + OFF_W2B);
  unsigned short* Gd  = (unsigned short*)(ws + OFF_W1B);  // alias: W1b dead after upproj
  unsigned short* G   = (unsigned short*)(ws + OFF_G);

  router_conv_kernel<<<RB_ROUTER + CB_CONV, 256, 0, stream>>>(
      x, Wg, bias, epair, wpair, Xb, W1, W1b, W3, W3b);

  compact_kernel<<<1, 512, 0, stream>>>(epair, wpair, cnt, base, rows, wts, t2s);

  dim3 g2(FFN_D / 64, T_TOK / 128, NE + 1);   // z==NE converts W2 concurrently
  upproj_fast<<<g2, 256, 0, stream>>>(Xb, W1b, W3b, cnt, base, rows, wts, G, W2, W2b);

  dim3 g3(H_DIM / 128, T_TOK / 128, NE);
  downproj_fast<<<g3, 256, 0, stream>>>(G, W2b, cnt, base, Gd);

  combine_kernel<<<T_TOK, 256, 0, stream>>>(Gd, base, t2s, out);
}